// Round 8
// baseline (22971.150 us; speedup 1.0000x reference)
//
#include <hip/hip_runtime.h>
#include <hip/hip_bf16.h>

// FARGAN vocoder on MI355X. Sizes fixed by the reference:
#define SS      64
#define NSUB    4
#define LPREV   512
#define NF      193
#define NFRAMES 100
#define BATCH   64
#define RPW     16     // batch rows per wave (MFMA N-side = batch rows)
#define HSTR    514    // hist row stride (u16)

typedef __attribute__((ext_vector_type(8))) short   short8;   // 8 bf16 (4 VGPRs)
typedef __attribute__((ext_vector_type(4))) float   floatx4;  // MFMA C/D

// ---------- scalar helpers ----------
__device__ __forceinline__ float bf2f(unsigned short u) {
    return __uint_as_float(((unsigned int)u) << 16);
}
__device__ __forceinline__ unsigned short f2bf(float x) {
    unsigned int u = __float_as_uint(x);
    return (unsigned short)((u + 0x7fffu + ((u >> 16) & 1u)) >> 16);
}
__device__ __forceinline__ unsigned int packbf(float a, float b) {
    return (unsigned int)f2bf(a) | ((unsigned int)f2bf(b) << 16);
}
__device__ __forceinline__ float fexp2(float x) {
#if __has_builtin(__builtin_amdgcn_exp2f)
    return __builtin_amdgcn_exp2f(x);
#else
    return exp2f(x);
#endif
}
__device__ __forceinline__ float frcp(float x) {
#if __has_builtin(__builtin_amdgcn_rcpf)
    return __builtin_amdgcn_rcpf(x);
#else
    return 1.0f / x;
#endif
}
__device__ __forceinline__ float fsig(float x) {
    return frcp(1.0f + fexp2(-1.442695041f * x));
}
__device__ __forceinline__ float ftanh(float x) {
    return fmaf(2.0f, frcp(1.0f + fexp2(-2.885390082f * x)), -1.0f);
}
__device__ __forceinline__ float ld1f(int f32, const void* p, size_t i) {
    if (f32) return ((const float*)p)[i];
    return bf2f(((const unsigned short*)p)[i]);
}
__device__ __forceinline__ float lo16(unsigned int u) { return __uint_as_float(u << 16); }
__device__ __forceinline__ float hi16(unsigned int u) { return __uint_as_float(u & 0xffff0000u); }

// packed f32->bf16 RNE conversion (1 instr / 2 values)
__device__ __forceinline__ unsigned int cvtpk(float lo, float hi) {
    unsigned int r;
    asm("v_cvt_pk_bf16_f32 %0, %1, %2" : "=v"(r) : "v"(lo), "v"(hi));
    return r;
}

// MFMA wrapper. In this kernel A = weight fragment, B = activation fragment,
// so C comes out TRANSPOSED: C[row=out-dim 4lq+r][col=batch-row ln].
__device__ __forceinline__ floatx4 mf(short8 a, short8 b, floatx4 c) {
    return __builtin_amdgcn_mfma_f32_16x16x32_bf16(a, b, c, 0, 0, 0);
}

// activation fragment from row-major packed-bf16 LDS buffer:
// lane (lq,ln) gets x[row=ln][k = kb*32 + lq*8 + j]. strideU in u32.
__device__ __forceinline__ short8 ldA(const unsigned short* buf, int strideU,
                                      int m, int kb, int q) {
    const unsigned int* p = (const unsigned int*)buf + m * strideU + kb * 16 + q * 4;
    uint4 u = *(const uint4*)p;
    return __builtin_bit_cast(short8, u);
}
// weight fragment from prepacked global buffer
__device__ __forceinline__ short8 ldB(const uint4* __restrict__ w, int idx) {
    return __builtin_bit_cast(short8, w[idx]);
}
// weight fragment from LDS copy
__device__ __forceinline__ short8 ldL(const uint4* w, int idx) {
    return __builtin_bit_cast(short8, w[idx]);
}

// compiler reorder fence (backend inserts actual waitcnts for LDS deps;
// hardware keeps per-wave DS ops in order, so no s_barrier is needed for
// same-wave cross-lane LDS communication)
__device__ __forceinline__ void fence() { asm volatile("" ::: "memory"); }

// store 4 transposed values (out-dims d0..d0+3, row ln) as 2 packed u32
__device__ __forceinline__ void stpair(unsigned short* p, float a, float b,
                                       float c, float d) {
    uint2 v; v.x = cvtpk(a, b); v.y = cvtpk(c, d);
    *(uint2*)p = v;
}

// weight-fragment pair (two 16-out-dim tiles) + loader + MFMA pair
template<int KB> struct WP { short8 a[KB]; short8 b[KB]; };
template<int KB>
__device__ __forceinline__ void wload(WP<KB>& w, const uint4* __restrict__ wb,
                                      int base0, int base1, int lane) {
#pragma unroll
    for (int k = 0; k < KB; ++k) {
        w.a[k] = ldB(wb, base0 + k * 64 + lane);
        w.b[k] = ldB(wb, base1 + k * 64 + lane);
    }
}
template<int KB>
__device__ __forceinline__ void wmm(const WP<KB>& w, const short8* bf,
                                    floatx4& Ca, floatx4& Cb) {
#pragma unroll
    for (int k = 0; k < KB; ++k) {
        Ca = mf(w.a[k], bf[k], Ca);
        Cb = mf(w.b[k], bf[k], Cb);
    }
}

// ---------- wbuf layout (units = 16B frags) ----------
#define OFF_FW   0        // 4t x 13kb
#define OFF_FWG  3328     // 4t x 2kb
#define OFF_GRU(G) (3840 + 4608*(G))   // r@+0(6kb) z@+1536(6kb) i@+3072(4kb) h@+4096(2kb)
#define OFF_WG(G)  (17664 + 512*(G))   // 4t x 2kb
#define OFF_SD   19200    // 8t x 10kb
#define OFF_SG   24320    // 8t x 4kb
#define OFF_OUT  26368    // 4t x 4kb
#define NFRAG    27392

// ---------- dtype detector ----------
__global__ void fargan_detect(const void* feats, int* flag) {
    const float* pf = (const float*)feats;
    int ok = 1;
    for (int f = 0; f < 50; ++f) {
        float v = pf[192 * NFRAMES + f];
        if (!(v >= 63.0f && v <= 301.0f)) { ok = 0; break; }
    }
    *flag = ok;
}

// ---------- weight prep: repack all seq weights into frag order ----------
__global__ __launch_bounds__(256) void fargan_prep(
    const int* __restrict__ flag,
    const void* Wfw, const void* Wfwg,
    const void* Wih1, const void* Whh1, const void* Wih2, const void* Whh2,
    const void* Wih3, const void* Whh3,
    const void* Wg1, const void* Wg2, const void* Wg3,
    const void* Wsg, const void* Wsd, const void* Wout,
    uint4* __restrict__ wbuf)
{
    int fi = blockIdx.x * 256 + threadIdx.x;
    if (fi >= NFRAG) return;
    int f32 = *flag;
    const void* mats[14] = {Wfw, Wfwg, Wih1, Whh1, Wih2, Whh2, Wih3, Whh3,
                            Wg1, Wg2, Wg3, Wsg, Wsd, Wout};
    const int NSEG = 20;
    const int sb[NSEG]  = {0,3328, 3840,5376,6912,7936, 8448,9984,11520,12544,
                           13056,14592,16128,17152, 17664,18176,18688, 19200,24320,26368};
    const int sa[NSEG]  = {0,1, 2,2,2,3, 4,4,4,5, 6,6,6,7, 8,9,10, 12,11,13};
    const int sbx[NSEG] = {-1,-1, 3,3,-1,-1, 5,5,-1,-1, 7,7,-1,-1, -1,-1,-1, -1,-1,-1};
    const int sro[NSEG] = {0,0, 0,64,128,128, 0,64,128,128, 0,64,128,128, 0,0,0, 0,0,0};
    const int skb[NSEG] = {13,2, 6,6,4,2, 6,6,4,2, 6,6,4,2, 2,2,2, 10,4,4};
    const int ska[NSEG] = {388,64, 128,128,128,64, 128,128,128,64, 128,128,128,64,
                           64,64,64, 320,128,128};
    const int skr[NSEG] = {388,64, 192,192,128,64, 192,192,128,64, 192,192,128,64,
                           64,64,64, 320,128,128};
    int s = 0;
    for (int i = 1; i < NSEG; ++i) if (fi >= sb[i]) s = i;
    int local = fi - sb[s];
    int ln = local & 15, lq = (local >> 4) & 3, tkb = local >> 6;
    int KB = skb[s];
    int kb = tkb % KB, tile = tkb / KB;
    int row = sro[s] + tile * 16 + ln;
    int Ka = ska[s], Kr = skr[s];
    union { unsigned short h[8]; uint4 v; } u;
#pragma unroll
    for (int j = 0; j < 8; ++j) {
        int k = kb * 32 + lq * 8 + j;
        unsigned short val = 0;
        if (k < Kr) {
            const void* m; size_t off;
            if (sbx[s] >= 0 && k >= Ka) { m = mats[sbx[s]]; off = (size_t)row * 64 + (k - Ka); }
            else                        { m = mats[sa[s]];  off = (size_t)row * Ka + k; }
            val = f32 ? f2bf(((const float*)m)[off]) : ((const unsigned short*)m)[off];
        }
        u.h[j] = val;
    }
    wbuf[fi] = u.v;
}

// ---------- prep: repack Wc1/2/3 transposed + bf16-pair packed ----------
__global__ __launch_bounds__(256) void fargan_prep_conv(
    const int* __restrict__ flag,
    const void* Wc1, const void* Wc2, const void* Wc3,
    unsigned int* __restrict__ wct)
{
    int idx = blockIdx.x * 256 + threadIdx.x;
    if (idx >= 131072) return;
    int f32 = *flag;
    const void* W; int n, k2;
    if (idx < 32768)      { W = Wc1; k2 = idx >> 8, n = idx & 255; }
    else if (idx < 65536) { W = Wc2; k2 = (idx - 32768) >> 8; n = idx & 255; }
    else                  { W = Wc3; k2 = (idx - 65536) >> 9; n = (idx - 65536) & 511; }
    size_t off = (size_t)n * 256 + 2 * k2;
    unsigned int v;
    if (f32) {
        const float* p = (const float*)W + off;
        v = packbf(p[0], p[1]);
    } else {
        v = *(const unsigned int*)((const unsigned short*)W + off);
    }
    wct[idx] = v;
}

// ---------- kernel 1: frame conv -> bf16 output cb16[b][f][k*128+j] ----------
template<bool F32>
__device__ __forceinline__ void conv_body(
    const void* __restrict__ feats, const void* __restrict__ gfeat,
    const unsigned int* __restrict__ wct, unsigned short* __restrict__ cb16)
{
    int blk = blockIdx.x;
    int b = blk / 25, fq = blk - b * 25;
    int f0 = fq * 4;
    int t = threadIdx.x;
    __shared__ float xa[4][256], xb[4][256];

#pragma unroll
    for (int j = 0; j < 4; ++j) {
        float v;
        if (t < 192) v = ld1f(F32 ? 1 : 0, feats, (size_t)b * (NF * NFRAMES) + t * NFRAMES + f0 + j);
        else         v = ld1f(F32 ? 1 : 0, gfeat, (size_t)b * 64 + (t - 192));
        xa[j][t] = v;
    }
    __syncthreads();

    const unsigned int* w1 = wct;
    const unsigned int* w2 = wct + 32768;
    const unsigned int* w3 = wct + 65536;

    float a0[4], a1[4], b0[4], b1[4];
#pragma unroll
    for (int j = 0; j < 4; ++j) { a0[j] = 0.f; a1[j] = 0.f; }
#pragma unroll 4
    for (int k2 = 0; k2 < 128; ++k2) {
        unsigned int u = w1[k2 * 256 + t];
        float lo = lo16(u), hi = hi16(u);
#pragma unroll
        for (int j = 0; j < 4; ++j) {
            a0[j] = fmaf(lo, xa[j][2 * k2], a0[j]);
            a1[j] = fmaf(hi, xa[j][2 * k2 + 1], a1[j]);
        }
    }
#pragma unroll
    for (int j = 0; j < 4; ++j) xb[j][t] = ftanh(a0[j] + a1[j]);
    __syncthreads();

#pragma unroll
    for (int j = 0; j < 4; ++j) { a0[j] = 0.f; a1[j] = 0.f; }
#pragma unroll 4
    for (int k2 = 0; k2 < 128; ++k2) {
        unsigned int u = w2[k2 * 256 + t];
        float lo = lo16(u), hi = hi16(u);
#pragma unroll
        for (int j = 0; j < 4; ++j) {
            a0[j] = fmaf(lo, xb[j][2 * k2], a0[j]);
            a1[j] = fmaf(hi, xb[j][2 * k2 + 1], a1[j]);
        }
    }
    __syncthreads();
#pragma unroll
    for (int j = 0; j < 4; ++j) xa[j][t] = ftanh(a0[j] + a1[j]);
    __syncthreads();

#pragma unroll
    for (int j = 0; j < 4; ++j) { a0[j] = 0.f; a1[j] = 0.f; b0[j] = 0.f; b1[j] = 0.f; }
#pragma unroll 4
    for (int k2 = 0; k2 < 128; ++k2) {
        unsigned int u  = w3[k2 * 512 + t];
        unsigned int u2 = w3[k2 * 512 + t + 256];
        float lo = lo16(u), hi = hi16(u), lo2 = lo16(u2), hi2 = hi16(u2);
#pragma unroll
        for (int j = 0; j < 4; ++j) {
            a0[j] = fmaf(lo,  xa[j][2 * k2],     a0[j]);
            a1[j] = fmaf(hi,  xa[j][2 * k2 + 1], a1[j]);
            b0[j] = fmaf(lo2, xa[j][2 * k2],     b0[j]);
            b1[j] = fmaf(hi2, xa[j][2 * k2 + 1], b1[j]);
        }
    }
    int e0 = t, e1 = t + 256;
#pragma unroll
    for (int j = 0; j < 4; ++j) {
        unsigned short* co = cb16 + ((size_t)b * NFRAMES + f0 + j) * 512;
        co[(e0 & 3) * 128 + (e0 >> 2)] = f2bf(ftanh(a0[j] + a1[j]));
        co[(e1 & 3) * 128 + (e1 >> 2)] = f2bf(ftanh(b0[j] + b1[j]));
    }
}

__global__ __launch_bounds__(256) void fargan_conv(
    const void* feats, const void* gfeat,
    const int* flag, const unsigned int* wct, unsigned short* cb16)
{
    if (*flag) conv_body<true>(feats, gfeat, wct, cb16);
    else       conv_body<false>(feats, gfeat, wct, cb16);
}

// ---------- kernel 2: sequential recurrence, zero-barrier single-wave ----------
// One wave (64 threads) owns 16 batch rows and the ENTIRE per-step chain.
// Swapped-operand MFMA (A = weight frag, B = activation frag) produces
// transposed outputs (out-dim, batch-row) so every layer's result is
// lane-local; LDS is a same-wave bounce buffer only (per-wave DS ordering,
// no s_barrier in the loop). SD weights (80 KB) live in LDS; the rest
// stream from wbuf (L2-resident) with in-phase prefetch. Grid = 4 waves,
// 1 wave/SIMD, 512-VGPR budget.

__global__ __launch_bounds__(64, 1)
void fargan_seq(
    const void* __restrict__ feats, const void* __restrict__ prev_in,
    const int* __restrict__ flag, const unsigned short* __restrict__ cb16,
    const uint4* __restrict__ wbuf, void* __restrict__ outp)
{
    const int lane = threadIdx.x;
    const int lq = lane >> 4, ln = lane & 15;
    const int b0 = blockIdx.x * RPW;
    const int f32 = *flag;
    const floatx4 z4 = {0.f, 0.f, 0.f, 0.f};

    // ---- LDS (~137 KB): state row-major [batch-row][dim] + SD weight copy ----
    __shared__ __align__(16) unsigned short hist[RPW * HSTR];   // sample ring
    __shared__ __align__(16) unsigned short catb[RPW * 424];    // FW input (212 u32)
    __shared__ __align__(16) unsigned short psb [RPW * 72];     // prev_sub
    __shared__ __align__(16) unsigned short sgb [3][RPW * 72];  // GRU states
    __shared__ __align__(16) unsigned short skx [RPW * 264];    // [o1|o2|o3|fw]
    __shared__ __align__(16) unsigned short v64 [RPW * 72];     // bounce
    __shared__ __align__(16) unsigned short sdbb[RPW * 136];
    __shared__ __align__(16) unsigned short sobb[RPW * 136];
    __shared__ __align__(16) uint4 wsdL[5120];                  // SD weights (80 KB)
    __shared__ int period_s[RPW];

    // ---- init ----
    for (int i = lane; i < 5120; i += 64) wsdL[i] = wbuf[OFF_SD + i];
    for (int i = lane; i < RPW * 424; i += 64) catb[i] = 0;
    for (int i = lane; i < RPW * 72;  i += 64) {
        psb[i] = 0; v64[i] = 0; sgb[0][i] = 0; sgb[1][i] = 0; sgb[2][i] = 0;
    }
    for (int i = lane; i < RPW * 264; i += 64) skx[i] = 0;
    for (int i = lane; i < RPW * 136; i += 64) { sdbb[i] = 0; sobb[i] = 0; }
    for (int i = lane; i < RPW * 512; i += 64) {
        int row = i >> 9, c = i & 511;
        hist[row * HSTR + c] = f2bf(ld1f(f32, prev_in, (size_t)(b0 + row) * LPREV + c));
    }
    __syncthreads();
    for (int i = lane; i < RPW * 64; i += 64) {
        int row = i >> 6, c = i & 63;
        unsigned short hh = hist[row * HSTR + 448 + c];
        psb [row * 72 + c] = hh;
        catb[row * 424 + 128 + c] = hh;
    }
    // feat2s step0 + prefetch step1: lane (lq,ln) handles row ln, u16 span lq*32
    uint4 pfc[4];
    {
        const unsigned short* cr = cb16 + ((size_t)(b0 + ln) * NFRAMES + 0) * 512;
#pragma unroll
        for (int j = 0; j < 4; ++j) {
            uint4 u = *(const uint4*)(cr + 0 * 128 + lq * 32 + j * 8);
            *(uint4*)((unsigned int*)catb + ln * 212 + lq * 16 + j * 4) = u;
            pfc[j] = *(const uint4*)(cr + 1 * 128 + lq * 32 + j * 8);
        }
    }
    float pper = 0.f;
    if (lane < RPW) {
        pper = ld1f(f32, feats, (size_t)(b0 + lane) * (NF * NFRAMES) + (NF - 1) * NFRAMES + 0);
        period_s[lane] = (int)rintf(pper);
    }
    __syncthreads();

    floatx4 svr[3][4];
#pragma unroll
    for (int G = 0; G < 3; ++G)
#pragma unroll
        for (int t = 0; t < 4; ++t) svr[G][t] = z4;

    int base = 0;
    for (int f = 0; f < NFRAMES; ++f) {
        for (int kk = 0; kk < NSUB; ++kk) {
            // ======== FW weight loads (latency covered by gather) ========
            WP<13> fwA, fwB;
            wload<13>(fwA, wbuf, OFF_FW + 0,       OFF_FW + 13 * 64, lane);
            wload<13>(fwB, wbuf, OFF_FW + 26 * 64, OFF_FW + 39 * 64, lane);

            // ======== lookback gather (4 lanes per row, 17 each) ========
            {
                int per = period_s[ln];
#pragma unroll
                for (int ii = 0; ii < 17; ++ii) {
                    int i = lq * 17 + ii;
                    if (i < 68) {
                        int idx = LPREV - per + i - 2;
                        if (idx >= LPREV) idx -= per;
                        catb[ln * 424 + 192 + i] = hist[ln * HSTR + ((base + idx) & 511)];
                    }
                }
            }
            fence();

            // ======== FW ========
            short8 bfw[13];
#pragma unroll
            for (int kb = 0; kb < 13; ++kb) bfw[kb] = ldA(catb, 212, ln, kb, lq);
            WP<2> fgA, fgB;
            wload<2>(fgA, wbuf, OFF_FWG + 0,      OFF_FWG + 2 * 64, lane);
            wload<2>(fgB, wbuf, OFF_FWG + 4 * 64, OFF_FWG + 6 * 64, lane);
            floatx4 Cf[4] = {z4, z4, z4, z4};
            wmm<13>(fwA, bfw, Cf[0], Cf[1]);
            wmm<13>(fwB, bfw, Cf[2], Cf[3]);

            WP<6> grA, grB;          // GRU0 r, loaded early
            wload<6>(grA, wbuf, OFF_GRU(0) + 0,       OFF_GRU(0) + 6 * 64,  lane);
            wload<6>(grB, wbuf, OFF_GRU(0) + 12 * 64, OFF_GRU(0) + 18 * 64, lane);

            float xr[4][4];
#pragma unroll
            for (int t = 0; t < 4; ++t) {
#pragma unroll
                for (int r = 0; r < 4; ++r) xr[t][r] = ftanh(Cf[t][r]);
                stpair(&v64[ln * 72 + 16 * t + 4 * lq], xr[t][0], xr[t][1], xr[t][2], xr[t][3]);
            }
            fence();

            // ======== FWG (glu) ========
            {
                short8 bfg[2];
                bfg[0] = ldA(v64, 36, ln, 0, lq);
                bfg[1] = ldA(v64, 36, ln, 1, lq);
                floatx4 Cg[4] = {z4, z4, z4, z4};
                wmm<2>(fgA, bfg, Cg[0], Cg[1]);
                wmm<2>(fgB, bfg, Cg[2], Cg[3]);
#pragma unroll
                for (int t = 0; t < 4; ++t) {
                    float o0 = xr[t][0] * fsig(Cg[t][0]);
                    float o1 = xr[t][1] * fsig(Cg[t][1]);
                    float o2 = xr[t][2] * fsig(Cg[t][2]);
                    float o3 = xr[t][3] * fsig(Cg[t][3]);
                    stpair(&skx[ln * 264 + 192 + 16 * t + 4 * lq], o0, o1, o2, o3);
                }
            }
            fence();

            // ======== GRU + GLU x3 ========
#pragma unroll
            for (int G = 0; G < 3; ++G) {
                const int OZ = OFF_GRU(G) + 1536;
                const int OI = OFF_GRU(G) + 3072;
                const int OH = OFF_GRU(G) + 4096;
                const int inkb = (G == 0) ? 6 : (G == 1) ? 0 : 2;

                WP<6> gz0, gz1;
                wload<6>(gz0, wbuf, OZ + 0,       OZ + 6 * 64,  lane);
                wload<6>(gz1, wbuf, OZ + 12 * 64, OZ + 18 * 64, lane);

                short8 bgr[6];
                bgr[0] = ldA(skx, 132, ln, inkb, lq);
                bgr[1] = ldA(skx, 132, ln, inkb + 1, lq);
                bgr[2] = ldA(psb, 36, ln, 0, lq);
                bgr[3] = ldA(psb, 36, ln, 1, lq);
                bgr[4] = ldA(sgb[G], 36, ln, 0, lq);
                bgr[5] = ldA(sgb[G], 36, ln, 1, lq);

                floatx4 Cr[4] = {z4, z4, z4, z4};
                floatx4 Cz[4] = {z4, z4, z4, z4};
                floatx4 Ci[4] = {z4, z4, z4, z4};
                floatx4 Ch[4] = {z4, z4, z4, z4};

                wmm<6>(grA, bgr, Cr[0], Cr[1]);
                WP<4> gi0, gi1;
                wload<4>(gi0, wbuf, OI + 0,      OI + 4 * 64,  lane);
                wmm<6>(grB, bgr, Cr[2], Cr[3]);
                wload<4>(gi1, wbuf, OI + 8 * 64, OI + 12 * 64, lane);
                wmm<6>(gz0, bgr, Cz[0], Cz[1]);
                WP<2> gh0, gh1;
                wload<2>(gh0, wbuf, OH + 0,      OH + 2 * 64, lane);
                wload<2>(gh1, wbuf, OH + 4 * 64, OH + 6 * 64, lane);
                wmm<6>(gz1, bgr, Cz[2], Cz[3]);
                wmm<4>(gi0, bgr, Ci[0], Ci[1]);
                wmm<4>(gi1, bgr, Ci[2], Ci[3]);
                wmm<2>(gh0, &bgr[4], Ch[0], Ch[1]);
                wmm<2>(gh1, &bgr[4], Ch[2], Ch[3]);
                WP<2> gl0, gl1;
                wload<2>(gl0, wbuf, OFF_WG(G) + 0,      OFF_WG(G) + 2 * 64, lane);
                wload<2>(gl1, wbuf, OFF_WG(G) + 4 * 64, OFF_WG(G) + 6 * 64, lane);

                float sn[4][4];
#pragma unroll
                for (int t = 0; t < 4; ++t) {
#pragma unroll
                    for (int r = 0; r < 4; ++r) {
                        float rr = fsig(Cr[t][r]);
                        float zz = fsig(Cz[t][r]);
                        float nn = ftanh(Ci[t][r] + rr * Ch[t][r]);
                        float s  = fmaf(zz, svr[G][t][r] - nn, nn);
                        svr[G][t][r] = s;
                        sn[t][r] = s;
                    }
                    stpair(&v64[ln * 72 + 16 * t + 4 * lq],
                           sn[t][0], sn[t][1], sn[t][2], sn[t][3]);
                    stpair(&sgb[G][ln * 72 + 16 * t + 4 * lq],
                           sn[t][0], sn[t][1], sn[t][2], sn[t][3]);
                }
                if (G < 2) {
                    const int ORn = OFF_GRU(G + 1);
                    wload<6>(grA, wbuf, ORn + 0,       ORn + 6 * 64,  lane);
                    wload<6>(grB, wbuf, ORn + 12 * 64, ORn + 18 * 64, lane);
                }
                fence();
                {
                    short8 bgl[2];
                    bgl[0] = ldA(v64, 36, ln, 0, lq);
                    bgl[1] = ldA(v64, 36, ln, 1, lq);
                    floatx4 Cl[4] = {z4, z4, z4, z4};
                    wmm<2>(gl0, bgl, Cl[0], Cl[1]);
                    wmm<2>(gl1, bgl, Cl[2], Cl[3]);
#pragma unroll
                    for (int t = 0; t < 4; ++t) {
                        float o0 = sn[t][0] * fsig(Cl[t][0]);
                        float o1 = sn[t][1] * fsig(Cl[t][1]);
                        float o2 = sn[t][2] * fsig(Cl[t][2]);
                        float o3 = sn[t][3] * fsig(Cl[t][3]);
                        stpair(&skx[ln * 264 + G * 64 + 16 * t + 4 * lq], o0, o1, o2, o3);
                    }
                }
                fence();
            }

            // ======== SD (tanh), out=128 (8 tiles), K=320, weights in LDS ========
            WP<4> sg0, sg1;
            wload<4>(sg0, wbuf, OFF_SG + 0,      OFF_SG + 4 * 64,  lane);
            wload<4>(sg1, wbuf, OFF_SG + 8 * 64, OFF_SG + 12 * 64, lane);
            short8 bsd[10];
#pragma unroll
            for (int k = 0; k < 8; ++k) bsd[k] = ldA(skx, 132, ln, k, lq);
            bsd[8] = ldA(psb, 36, ln, 0, lq);
            bsd[9] = ldA(psb, 36, ln, 1, lq);
            floatx4 Cs[8] = {z4, z4, z4, z4, z4, z4, z4, z4};
#pragma unroll
            for (int tp = 0; tp < 4; ++tp) {
                WP<10> sdw;
#pragma unroll
                for (int k = 0; k < 10; ++k) {
                    sdw.a[k] = ldL(wsdL, ((2 * tp + 0) * 10 + k) * 64 + lane);
                    sdw.b[k] = ldL(wsdL, ((2 * tp + 1) * 10 + k) * 64 + lane);
                }
                wmm<10>(sdw, bsd, Cs[2 * tp], Cs[2 * tp + 1]);
            }

            float sdv[8][4];
#pragma unroll
            for (int t = 0; t < 8; ++t) {
#pragma unroll
                for (int r = 0; r < 4; ++r) sdv[t][r] = ftanh(Cs[t][r]);
                stpair(&sdbb[ln * 136 + 16 * t + 4 * lq],
                       sdv[t][0], sdv[t][1], sdv[t][2], sdv[t][3]);
            }
            fence();

            // ======== SG (glu), out=128 ========
            {
                short8 bsg[4];
#pragma unroll
                for (int k = 0; k < 4; ++k) bsg[k] = ldA(sdbb, 68, ln, k, lq);
                floatx4 Cq[8] = {z4, z4, z4, z4, z4, z4, z4, z4};
                wmm<4>(sg0, bsg, Cq[0], Cq[1]);
                wload<4>(sg0, wbuf, OFF_SG + 16 * 64, OFF_SG + 20 * 64, lane);
                wmm<4>(sg1, bsg, Cq[2], Cq[3]);
                WP<4> otA, otB;
                wload<4>(otA, wbuf, OFF_OUT + 0,      OFF_OUT + 4 * 64,  lane);
                wload<4>(otB, wbuf, OFF_OUT + 8 * 64, OFF_OUT + 12 * 64, lane);
                wmm<4>(sg0, bsg, Cq[4], Cq[5]);
                wload<4>(sg1, wbuf, OFF_SG + 24 * 64, OFF_SG + 28 * 64, lane);
                wmm<4>(sg1, bsg, Cq[6], Cq[7]);
#pragma unroll
                for (int t = 0; t < 8; ++t) {
                    float o0 = sdv[t][0] * fsig(Cq[t][0]);
                    float o1 = sdv[t][1] * fsig(Cq[t][1]);
                    float o2 = sdv[t][2] * fsig(Cq[t][2]);
                    float o3 = sdv[t][3] * fsig(Cq[t][3]);
                    stpair(&sobb[ln * 136 + 16 * t + 4 * lq], o0, o1, o2, o3);
                }
                fence();

                // ======== OUT (tanh) + stores + next-step staging ========
                short8 bo[4];
#pragma unroll
                for (int k = 0; k < 4; ++k) bo[k] = ldA(sobb, 68, ln, k, lq);
                floatx4 Co[4] = {z4, z4, z4, z4};
                wmm<4>(otA, bo, Co[0], Co[1]);
                wmm<4>(otB, bo, Co[2], Co[3]);
#pragma unroll
                for (int t = 0; t < 4; ++t) {
                    float ov[4];
#pragma unroll
                    for (int r = 0; r < 4; ++r) ov[r] = ftanh(Co[t][r]);
                    unsigned int q01 = cvtpk(ov[0], ov[1]);
                    unsigned int q23 = cvtpk(ov[2], ov[3]);
                    int d0 = 16 * t + 4 * lq;
                    int hc = (base + d0) & 511;
                    *(unsigned int*)&hist[ln * HSTR + hc]     = q01;
                    *(unsigned int*)&hist[ln * HSTR + hc + 2] = q23;
                    uint2 qq; qq.x = q01; qq.y = q23;
                    *(uint2*)&catb[ln * 424 + 128 + d0] = qq;
                    *(uint2*)&psb [ln * 72 + d0]        = qq;
                    size_t ob = (size_t)(b0 + ln) * (NFRAMES * NSUB * SS)
                              + f * (NSUB * SS) + kk * SS + d0;
                    if (f32) {
                        float4 v4; v4.x = ov[0]; v4.y = ov[1]; v4.z = ov[2]; v4.w = ov[3];
                        *(float4*)((float*)outp + ob) = v4;
                    } else {
                        *(uint2*)((unsigned short*)outp + ob) = qq;
                    }
                }
            }
            // feat2s shuffle + prefetch + period
            {
                unsigned int* c32 = (unsigned int*)catb + ln * 212;
                int u0 = lq * 16;
#pragma unroll
                for (int j = 0; j < 16; ++j) c32[130 + u0 + j] = c32[u0 + j];
#pragma unroll
                for (int j = 0; j < 4; ++j) *(uint4*)(c32 + u0 + j * 4) = pfc[j];
                int sN = f * 4 + kk + 2;
                if (sN > NFRAMES * 4 - 1) sN = NFRAMES * 4 - 1;
                const unsigned short* cr = cb16
                    + ((size_t)(b0 + ln) * NFRAMES + (sN >> 2)) * 512 + (sN & 3) * 128;
#pragma unroll
                for (int j = 0; j < 4; ++j) pfc[j] = *(const uint4*)(cr + lq * 32 + j * 8);
                if (kk == 0 && lane < RPW) {
                    int fN = (f + 1 < NFRAMES) ? f + 1 : f;
                    pper = ld1f(f32, feats,
                                (size_t)(b0 + lane) * (NF * NFRAMES) + (NF - 1) * NFRAMES + fN);
                }
                if (kk == 3 && lane < RPW) period_s[lane] = (int)rintf(pper);
            }
            fence();
            base += SS;
        }
    }
}

// ---------- launch ----------
extern "C" void kernel_launch(void* const* d_in, const int* in_sizes, int n_in,
                              void* d_out, int out_size, void* d_ws, size_t ws_size,
                              hipStream_t stream) {
    const void* feats = d_in[0];
    const void* gfeat = d_in[1];
    const void* prev  = d_in[2];
    const void* Wc1   = d_in[3];
    const void* Wc2   = d_in[4];
    const void* Wc3   = d_in[5];
    const void* Wfw   = d_in[6];
    const void* Wfwg  = d_in[7];
    const void* Wih1  = d_in[8];
    const void* Whh1  = d_in[9];
    const void* Wih2  = d_in[10];
    const void* Whh2  = d_in[11];
    const void* Wih3  = d_in[12];
    const void* Whh3  = d_in[13];
    const void* Wg1   = d_in[14];
    const void* Wg2   = d_in[15];
    const void* Wg3   = d_in[16];
    const void* Wsg   = d_in[17];
    const void* Wsd   = d_in[18];
    const void* Wout  = d_in[19];

    int*            flag = (int*)d_ws;                                      // @0
    unsigned short* cb16 = (unsigned short*)((char*)d_ws + 256);            // 6,553,600 B
    unsigned int*   wct  = (unsigned int*)((char*)d_ws + 256 + 6553600);    // 524,288 B
    uint4*          wbuf = (uint4*)((char*)d_ws + 256 + 6553600 + 524288);  // 438,272 B

    fargan_detect<<<1, 1, 0, stream>>>(feats, flag);
    fargan_prep<<<(NFRAG + 255) / 256, 256, 0, stream>>>(flag, Wfw, Wfwg,
        Wih1, Whh1, Wih2, Whh2, Wih3, Whh3, Wg1, Wg2, Wg3, Wsg, Wsd, Wout, wbuf);
    fargan_prep_conv<<<512, 256, 0, stream>>>(flag, Wc1, Wc2, Wc3, wct);
    fargan_conv<<<BATCH * 25, 256, 0, stream>>>(feats, gfeat, flag, wct, cb16);
    fargan_seq<<<BATCH / RPW, 64, 0, stream>>>(feats, prev, flag, cb16, wbuf, d_out);
}

// Round 9
// 2226.188 us; speedup vs baseline: 10.3186x; 10.3186x over previous
//
#include <hip/hip_runtime.h>
#include <hip/hip_bf16.h>

// FARGAN vocoder on MI355X. Sizes fixed by the reference:
#define SS      64
#define NSUB    4
#define LPREV   512
#define NF      193
#define NFRAMES 100
#define BATCH   64
#define RPW     16     // batch rows per workgroup (MFMA M)
#define HSTR    514    // hist row stride (u16); odd u32 stride -> bank stagger

typedef __attribute__((ext_vector_type(8))) short   short8;   // 8 bf16 (4 VGPRs)
typedef __attribute__((ext_vector_type(4))) float   floatx4;  // MFMA C/D

// ---------- scalar helpers ----------
__device__ __forceinline__ float bf2f(unsigned short u) {
    return __uint_as_float(((unsigned int)u) << 16);
}
__device__ __forceinline__ unsigned short f2bf(float x) {
    unsigned int u = __float_as_uint(x);
    return (unsigned short)((u + 0x7fffu + ((u >> 16) & 1u)) >> 16);
}
__device__ __forceinline__ unsigned int packbf(float a, float b) {
    return (unsigned int)f2bf(a) | ((unsigned int)f2bf(b) << 16);
}
__device__ __forceinline__ float fexp2(float x) {
#if __has_builtin(__builtin_amdgcn_exp2f)
    return __builtin_amdgcn_exp2f(x);
#else
    return exp2f(x);
#endif
}
__device__ __forceinline__ float frcp(float x) {
#if __has_builtin(__builtin_amdgcn_rcpf)
    return __builtin_amdgcn_rcpf(x);
#else
    return 1.0f / x;
#endif
}
__device__ __forceinline__ float fsig(float x) {
    return frcp(1.0f + fexp2(-1.442695041f * x));
}
__device__ __forceinline__ float ftanh(float x) {
    return fmaf(2.0f, frcp(1.0f + fexp2(-2.885390082f * x)), -1.0f);
}
__device__ __forceinline__ float ld1f(int f32, const void* p, size_t i) {
    if (f32) return ((const float*)p)[i];
    return bf2f(((const unsigned short*)p)[i]);
}
__device__ __forceinline__ float lo16(unsigned int u) { return __uint_as_float(u << 16); }
__device__ __forceinline__ float hi16(unsigned int u) { return __uint_as_float(u & 0xffff0000u); }

// packed f32->bf16 RNE conversion (1 instr / 2 values)
__device__ __forceinline__ unsigned int cvtpk(float lo, float hi) {
    unsigned int r;
    asm("v_cvt_pk_bf16_f32 %0, %1, %2" : "=v"(r) : "v"(lo), "v"(hi));
    return r;
}
// store 4 values down a column (rows +0..+3): 2 cvt_pk + 4 b16 stores
__device__ __forceinline__ void st4c(unsigned short* p, int strideU16,
                                     float a, float b, float c, float d) {
    unsigned int p01 = cvtpk(a, b), p23 = cvtpk(c, d);
    p[0]             = (unsigned short)p01;
    p[strideU16]     = (unsigned short)(p01 >> 16);
    p[2 * strideU16] = (unsigned short)p23;
    p[3 * strideU16] = (unsigned short)(p23 >> 16);
}

// MFMA wrapper
__device__ __forceinline__ floatx4 mf(short8 a, short8 b, floatx4 c) {
    return __builtin_amdgcn_mfma_f32_16x16x32_bf16(a, b, c, 0, 0, 0);
}

// A-fragment from packed-bf16 LDS buffer: row m, k-block kb, quad q. strideU in u32.
__device__ __forceinline__ short8 ldA(const unsigned short* buf, int strideU,
                                      int m, int kb, int q) {
    const unsigned int* p = (const unsigned int*)buf + m * strideU + kb * 16 + q * 4;
    uint4 u = *(const uint4*)p;
    return __builtin_bit_cast(short8, u);
}
// B-fragment from prepacked weight buffer (global, L2-hot)
__device__ __forceinline__ short8 ldB(const uint4* __restrict__ w, int idx) {
    return __builtin_bit_cast(short8, w[idx]);
}

// lgkm-only barrier: does NOT drain vmcnt, so GLOBAL weight prefetches and
// output stores stay in flight across phases. Memory clobbers keep the
// compiler from moving LDS ops across.
__device__ __forceinline__ void barx() {
    asm volatile("s_waitcnt lgkmcnt(0)" ::: "memory");
    __builtin_amdgcn_s_barrier();
    asm volatile("" ::: "memory");
}

// ---------- wbuf layout (units = 16B frags) ----------
#define OFF_FW   0        // 4t x 13kb
#define OFF_FWG  3328     // 4t x 2kb
#define OFF_GRU(G) (3840 + 4608*(G))   // r@+0(6kb) z@+1536(6kb) i@+3072(4kb) h@+4096(2kb)
#define OFF_WG(G)  (17664 + 512*(G))   // 4t x 2kb
#define OFF_SD   19200    // 8t x 10kb
#define OFF_SG   24320    // 8t x 4kb
#define OFF_OUT  26368    // 4t x 4kb
#define NFRAG    27392

// ---------- dtype detector ----------
__global__ void fargan_detect(const void* feats, int* flag) {
    const float* pf = (const float*)feats;
    int ok = 1;
    for (int f = 0; f < 50; ++f) {
        float v = pf[192 * NFRAMES + f];
        if (!(v >= 63.0f && v <= 301.0f)) { ok = 0; break; }
    }
    *flag = ok;
}

// ---------- weight prep: repack all seq weights into frag order ----------
__global__ __launch_bounds__(256) void fargan_prep(
    const int* __restrict__ flag,
    const void* Wfw, const void* Wfwg,
    const void* Wih1, const void* Whh1, const void* Wih2, const void* Whh2,
    const void* Wih3, const void* Whh3,
    const void* Wg1, const void* Wg2, const void* Wg3,
    const void* Wsg, const void* Wsd, const void* Wout,
    uint4* __restrict__ wbuf)
{
    int fi = blockIdx.x * 256 + threadIdx.x;
    if (fi >= NFRAG) return;
    int f32 = *flag;
    const void* mats[14] = {Wfw, Wfwg, Wih1, Whh1, Wih2, Whh2, Wih3, Whh3,
                            Wg1, Wg2, Wg3, Wsg, Wsd, Wout};
    const int NSEG = 20;
    const int sb[NSEG]  = {0,3328, 3840,5376,6912,7936, 8448,9984,11520,12544,
                           13056,14592,16128,17152, 17664,18176,18688, 19200,24320,26368};
    const int sa[NSEG]  = {0,1, 2,2,2,3, 4,4,4,5, 6,6,6,7, 8,9,10, 12,11,13};
    const int sbx[NSEG] = {-1,-1, 3,3,-1,-1, 5,5,-1,-1, 7,7,-1,-1, -1,-1,-1, -1,-1,-1};
    const int sro[NSEG] = {0,0, 0,64,128,128, 0,64,128,128, 0,64,128,128, 0,0,0, 0,0,0};
    const int skb[NSEG] = {13,2, 6,6,4,2, 6,6,4,2, 6,6,4,2, 2,2,2, 10,4,4};
    const int ska[NSEG] = {388,64, 128,128,128,64, 128,128,128,64, 128,128,128,64,
                           64,64,64, 320,128,128};
    const int skr[NSEG] = {388,64, 192,192,128,64, 192,192,128,64, 192,192,128,64,
                           64,64,64, 320,128,128};
    int s = 0;
    for (int i = 1; i < NSEG; ++i) if (fi >= sb[i]) s = i;
    int local = fi - sb[s];
    int ln = local & 15, lq = (local >> 4) & 3, tkb = local >> 6;
    int KB = skb[s];
    int kb = tkb % KB, tile = tkb / KB;
    int row = sro[s] + tile * 16 + ln;
    int Ka = ska[s], Kr = skr[s];
    union { unsigned short h[8]; uint4 v; } u;
#pragma unroll
    for (int j = 0; j < 8; ++j) {
        int k = kb * 32 + lq * 8 + j;
        unsigned short val = 0;
        if (k < Kr) {
            const void* m; size_t off;
            if (sbx[s] >= 0 && k >= Ka) { m = mats[sbx[s]]; off = (size_t)row * 64 + (k - Ka); }
            else                        { m = mats[sa[s]];  off = (size_t)row * Ka + k; }
            val = f32 ? f2bf(((const float*)m)[off]) : ((const unsigned short*)m)[off];
        }
        u.h[j] = val;
    }
    wbuf[fi] = u.v;
}

// ---------- prep: repack Wc1/2/3 transposed + bf16-pair packed ----------
__global__ __launch_bounds__(256) void fargan_prep_conv(
    const int* __restrict__ flag,
    const void* Wc1, const void* Wc2, const void* Wc3,
    unsigned int* __restrict__ wct)
{
    int idx = blockIdx.x * 256 + threadIdx.x;
    if (idx >= 131072) return;
    int f32 = *flag;
    const void* W; int n, k2;
    if (idx < 32768)      { W = Wc1; k2 = idx >> 8, n = idx & 255; }
    else if (idx < 65536) { W = Wc2; k2 = (idx - 32768) >> 8; n = idx & 255; }
    else                  { W = Wc3; k2 = (idx - 65536) >> 9; n = (idx - 65536) & 511; }
    size_t off = (size_t)n * 256 + 2 * k2;
    unsigned int v;
    if (f32) {
        const float* p = (const float*)W + off;
        v = packbf(p[0], p[1]);
    } else {
        v = *(const unsigned int*)((const unsigned short*)W + off);
    }
    wct[idx] = v;
}

// ---------- kernel 1: frame conv -> bf16 output cb16[b][f][k*128+j] ----------
template<bool F32>
__device__ __forceinline__ void conv_body(
    const void* __restrict__ feats, const void* __restrict__ gfeat,
    const unsigned int* __restrict__ wct, unsigned short* __restrict__ cb16)
{
    int blk = blockIdx.x;
    int b = blk / 25, fq = blk - b * 25;
    int f0 = fq * 4;
    int t = threadIdx.x;
    __shared__ float xa[4][256], xb[4][256];

#pragma unroll
    for (int j = 0; j < 4; ++j) {
        float v;
        if (t < 192) v = ld1f(F32 ? 1 : 0, feats, (size_t)b * (NF * NFRAMES) + t * NFRAMES + f0 + j);
        else         v = ld1f(F32 ? 1 : 0, gfeat, (size_t)b * 64 + (t - 192));
        xa[j][t] = v;
    }
    __syncthreads();

    const unsigned int* w1 = wct;
    const unsigned int* w2 = wct + 32768;
    const unsigned int* w3 = wct + 65536;

    float a0[4], a1[4], b0[4], b1[4];
#pragma unroll
    for (int j = 0; j < 4; ++j) { a0[j] = 0.f; a1[j] = 0.f; }
#pragma unroll 4
    for (int k2 = 0; k2 < 128; ++k2) {
        unsigned int u = w1[k2 * 256 + t];
        float lo = lo16(u), hi = hi16(u);
#pragma unroll
        for (int j = 0; j < 4; ++j) {
            a0[j] = fmaf(lo, xa[j][2 * k2], a0[j]);
            a1[j] = fmaf(hi, xa[j][2 * k2 + 1], a1[j]);
        }
    }
#pragma unroll
    for (int j = 0; j < 4; ++j) xb[j][t] = ftanh(a0[j] + a1[j]);
    __syncthreads();

#pragma unroll
    for (int j = 0; j < 4; ++j) { a0[j] = 0.f; a1[j] = 0.f; }
#pragma unroll 4
    for (int k2 = 0; k2 < 128; ++k2) {
        unsigned int u = w2[k2 * 256 + t];
        float lo = lo16(u), hi = hi16(u);
#pragma unroll
        for (int j = 0; j < 4; ++j) {
            a0[j] = fmaf(lo, xb[j][2 * k2], a0[j]);
            a1[j] = fmaf(hi, xb[j][2 * k2 + 1], a1[j]);
        }
    }
    __syncthreads();
#pragma unroll
    for (int j = 0; j < 4; ++j) xa[j][t] = ftanh(a0[j] + a1[j]);
    __syncthreads();

#pragma unroll
    for (int j = 0; j < 4; ++j) { a0[j] = 0.f; a1[j] = 0.f; b0[j] = 0.f; b1[j] = 0.f; }
#pragma unroll 4
    for (int k2 = 0; k2 < 128; ++k2) {
        unsigned int u  = w3[k2 * 512 + t];
        unsigned int u2 = w3[k2 * 512 + t + 256];
        float lo = lo16(u), hi = hi16(u), lo2 = lo16(u2), hi2 = hi16(u2);
#pragma unroll
        for (int j = 0; j < 4; ++j) {
            a0[j] = fmaf(lo,  xa[j][2 * k2],     a0[j]);
            a1[j] = fmaf(hi,  xa[j][2 * k2 + 1], a1[j]);
            b0[j] = fmaf(lo2, xa[j][2 * k2],     b0[j]);
            b1[j] = fmaf(hi2, xa[j][2 * k2 + 1], b1[j]);
        }
    }
    int e0 = t, e1 = t + 256;
#pragma unroll
    for (int j = 0; j < 4; ++j) {
        unsigned short* co = cb16 + ((size_t)b * NFRAMES + f0 + j) * 512;
        co[(e0 & 3) * 128 + (e0 >> 2)] = f2bf(ftanh(a0[j] + a1[j]));
        co[(e1 & 3) * 128 + (e1 >> 2)] = f2bf(ftanh(b0[j] + b1[j]));
    }
}

__global__ __launch_bounds__(256) void fargan_conv(
    const void* feats, const void* gfeat,
    const int* flag, const unsigned int* wct, unsigned short* cb16)
{
    if (*flag) conv_body<true>(feats, gfeat, wct, cb16);
    else       conv_body<false>(feats, gfeat, wct, cb16);
}

// ---------- kernel 2: sequential recurrence ----------
// Producer/consumer wave specialization (8 waves, 2/SIMD), best-known phase
// structure (R5 = 1758 us) with ONE change: producer's SD weight prefetch
// reads GLOBAL wbuf (vmcnt) instead of an LDS wsd copy (lgkm). barx drains
// lgkmcnt only, so the weight prefetch now genuinely crosses barriers
// instead of being drained at each phase end; the 84 KB wsd LDS copy and
// its staging are gone (LDS ~70 KB).

__global__ __launch_bounds__(512) __attribute__((amdgpu_waves_per_eu(2, 2)))
void fargan_seq(
    const void* __restrict__ feats, const void* __restrict__ prev_in,
    const int* __restrict__ flag, const unsigned short* __restrict__ cb16,
    const uint4* __restrict__ wbuf, void* __restrict__ outp)
{
    const int t = threadIdx.x;
    const int b0 = blockIdx.x * RPW;
    const int f32 = *flag;

    // ---- LDS (~70 KB) ----
    __shared__ __align__(16) unsigned short hist[RPW * HSTR];  // bf16 ring, mod-512
    __shared__ __align__(16) unsigned short catb[RPW * 424];   // [feat2s|ps|look|sfw|pad]
    __shared__ __align__(16) unsigned short psb [RPW * 72];    // prev_sub (once)
    __shared__ __align__(16) unsigned short sgb [RPW * 72];    // staged GRU state
    __shared__ __align__(16) unsigned short skx [RPW * 264];   // [o1|o2|o3|fw]
    __shared__ __align__(16) unsigned short sdbb[RPW * 136];
    __shared__ __align__(16) unsigned short sobb[RPW * 136];
    __shared__ __align__(16) unsigned short v64 [RPW * 72];
    __shared__ __align__(16) float pcFW[4][64][4];             // FW partial (P->C)
    __shared__ __align__(16) float pcG [4][64][3][4];          // GRU partials r,z,h
    __shared__ int period_s[RPW];

    // ---- zero init LDS state + hist fill ----
    for (int i = t; i < RPW * 424; i += 512) catb[i] = 0;
    for (int i = t; i < RPW * 72;  i += 512) { psb[i] = 0; sgb[i] = 0; v64[i] = 0; }
    for (int i = t; i < RPW * 264; i += 512) skx[i] = 0;
    for (int i = t; i < RPW * 136; i += 512) { sdbb[i] = 0; sobb[i] = 0; }
    for (int i = t; i < RPW * 512; i += 512) {
        int row = i >> 9, c = i & 511;
        hist[row * HSTR + c] = f2bf(ld1f(f32, prev_in, (size_t)(b0 + row) * LPREV + c));
    }
    __syncthreads();
    // initial prev_sub (step 0): window[448..511] of prev_in -> psb
    for (int i = t; i < RPW * 64; i += 512) {
        int row = i >> 6, c = i & 63;
        psb[row * 72 + c] = hist[row * HSTR + 448 + c];
    }

    // producer staging mapping (threads 256..511: 16 threads/row, 8 bf16 each)
    const int prow = (t & 255) >> 4, px16 = t & 15, pe8 = (t & 15) * 8;
    uint4 pfc = {0, 0, 0, 0};
    float pper = 0.f;
    if (t >= 256) {
        // feat2s(step 0) synchronous write; prefetch feat2s(step 1)
        uint4 u0 = *(const uint4*)(cb16 + ((size_t)(b0 + prow) * NFRAMES + 0) * 512 + 0 * 128 + pe8);
        *(uint4*)((unsigned int*)catb + prow * 212 + (pe8 >> 1)) = u0;
        pfc = *(const uint4*)(cb16 + ((size_t)(b0 + prow) * NFRAMES + 0) * 512 + 1 * 128 + pe8);
        if (t < 256 + RPW) {
            pper = ld1f(f32, feats, (size_t)(b0 + (t - 256)) * (NF * NFRAMES) + (NF - 1) * NFRAMES + 0);
            period_s[t - 256] = (int)rintf(pper);
        }
    }
    __syncthreads();

    const floatx4 z4 = {0.f, 0.f, 0.f, 0.f};

    if (t < 256) {
        // ======================= CONSUMER (waves 0-3) =======================
        const int lane = t & 63, w = t >> 6;
        const int lq = lane >> 4, ln = lane & 15;
        const int nj = 16 * w + ln;
        const int n0 = 32 * w + ln, n1 = n0 + 16;
        const int m0 = 4 * lq;

        // resident B-frags: FW kb6-8 (finish) + kb9-12 (sfw, phase A)
        short8 BfwC[3], BfwA[4], Bfwg[2], Bout[4];
        short8 BrC[3][2], BzC[3][2], BiC[3][4], Bg[3][2];
        short8 Bsg0[4];                                   // SG tile0 only
#pragma unroll
        for (int j = 0; j < 3; ++j) BfwC[j] = ldB(wbuf, OFF_FW + (w * 13 + 6 + j) * 64 + lane);
#pragma unroll
        for (int j = 0; j < 4; ++j) BfwA[j] = ldB(wbuf, OFF_FW + (w * 13 + 9 + j) * 64 + lane);
#pragma unroll
        for (int kb = 0; kb < 2; ++kb) Bfwg[kb] = ldB(wbuf, OFF_FWG + (w * 2 + kb) * 64 + lane);
#pragma unroll
        for (int G = 0; G < 3; ++G) {
            const int OR = OFF_GRU(G), OZ = OR + 1536, OI = OR + 3072;
#pragma unroll
            for (int kb = 0; kb < 2; ++kb) {
                BrC[G][kb] = ldB(wbuf, OR + (w * 6 + kb) * 64 + lane);
                BzC[G][kb] = ldB(wbuf, OZ + (w * 6 + kb) * 64 + lane);
                Bg[G][kb]  = ldB(wbuf, OFF_WG(G) + (w * 2 + kb) * 64 + lane);
            }
#pragma unroll
            for (int kb = 0; kb < 4; ++kb) BiC[G][kb] = ldB(wbuf, OI + (w * 4 + kb) * 64 + lane);
        }
#pragma unroll
        for (int kb = 0; kb < 4; ++kb)
            Bsg0[kb] = ldB(wbuf, OFF_SG + ((2 * w + 0) * 4 + kb) * 64 + lane);
#pragma unroll
        for (int kb = 0; kb < 4; ++kb) Bout[kb] = ldB(wbuf, OFF_OUT + (w * 4 + kb) * 64 + lane);

        floatx4 svr[3];
#pragma unroll
        for (int G = 0; G < 3; ++G) svr[G] = z4;

        // pointer-incremented output indices (one per r)
        size_t oi[4];
#pragma unroll
        for (int r = 0; r < 4; ++r)
            oi[r] = (size_t)(b0 + m0 + r) * (NFRAMES * NSUB * SS) + nj;

        int base = 0;
        for (int f = 0; f < NFRAMES; ++f) {
            for (int kk = 0; kk < NSUB; ++kk) {
                // ====== A: FW sfw segment (kb9-12) + step-constant ps preload ======
                floatx4 C0 = z4, C1 = z4, C2 = z4, C3 = z4;
                short8 cps0 = ldA(psb, 36, ln, 0, lq);
                short8 cps1 = ldA(psb, 36, ln, 1, lq);
                {
                    short8 c9 = ldA(catb, 212, ln,  9, lq);
                    short8 cA = ldA(catb, 212, ln, 10, lq);
                    short8 cB = ldA(catb, 212, ln, 11, lq);
                    short8 cC = ldA(catb, 212, ln, 12, lq);
                    C2 = mf(c9, BfwA[0], C2);
                    C3 = mf(cA, BfwA[1], C3);
                    C0 = mf(cB, BfwA[2], C0);
                    C1 = mf(cC, BfwA[3], C1);
                }
                barx();                                    // A
                // ====== B: FW finish (kb6-8) + producer partial + tanh -> v64 ======
                float xr[4];
                {
                    __builtin_amdgcn_s_setprio(1);
                    short8 a6 = ldA(catb, 212, ln, 6, lq);
                    short8 a7 = ldA(catb, 212, ln, 7, lq);
                    short8 a8 = ldA(catb, 212, ln, 8, lq);
                    floatx4 pf = *(const floatx4*)&pcFW[w][lane][0];
                    C0 = mf(a6, BfwC[0], C0);
                    C1 = mf(a7, BfwC[1], C1);
                    C2 = mf(a8, BfwC[2], C2);
#pragma unroll
                    for (int r = 0; r < 4; ++r)
                        xr[r] = ftanh((C0[r] + C1[r]) + (C2[r] + C3[r] + pf[r]));
                    st4c(&v64[m0 * 72 + nj], 72, xr[0], xr[1], xr[2], xr[3]);
                    __builtin_amdgcn_s_setprio(0);
                }
                barx();                                    // B
                // ====== C: FWG glu -> skx fw ======
                {
                    short8 a0 = ldA(v64, 36, ln, 0, lq);
                    short8 a1 = ldA(v64, 36, ln, 1, lq);
                    floatx4 C = mf(a0, Bfwg[0], z4);
                    C = mf(a1, Bfwg[1], C);
                    float o0 = xr[0] * fsig(C[0]), o1 = xr[1] * fsig(C[1]);
                    float o2 = xr[2] * fsig(C[2]), o3 = xr[3] * fsig(C[3]);
                    st4c(&skx[m0 * 264 + 192 + nj], 264, o0, o1, o2, o3);
                }
                barx();                                    // C
                // ====== GRU finish + GLU x3 ======
#pragma unroll
                for (int G = 0; G < 3; ++G) {
                    {
                        __builtin_amdgcn_s_setprio(1);
                        const int inkb = (G == 0) ? 6 : (G == 1) ? 0 : 2;
                        short8 a0 = ldA(skx, 132, ln, inkb, lq);
                        short8 a1 = ldA(skx, 132, ln, inkb + 1, lq);
                        floatx4 pr = *(const floatx4*)&pcG[w][lane][0][0];
                        floatx4 pz = *(const floatx4*)&pcG[w][lane][1][0];
                        floatx4 ph = *(const floatx4*)&pcG[w][lane][2][0];
                        floatx4 Ci = mf(cps0, BiC[G][2], z4);
                        Ci = mf(cps1, BiC[G][3], Ci);
                        floatx4 Cr = mf(a0, BrC[G][0], z4);
                        floatx4 Cz = mf(a0, BzC[G][0], z4);
                        Ci = mf(a0, BiC[G][0], Ci);
                        Cr = mf(a1, BrC[G][1], Cr);
                        Cz = mf(a1, BzC[G][1], Cz);
                        Ci = mf(a1, BiC[G][1], Ci);
                        float sn[4];
#pragma unroll
                        for (int r = 0; r < 4; ++r) {
                            float rr = fsig(Cr[r] + pr[r]);
                            float zz = fsig(Cz[r] + pz[r]);
                            float nn = ftanh(Ci[r] + rr * ph[r]);
                            sn[r] = fmaf(zz, svr[G][r] - nn, nn);
                            svr[G][r] = sn[r];
                        }
                        st4c(&v64[m0 * 72 + nj], 72, sn[0], sn[1], sn[2], sn[3]);
                        if (G < 2)
                            st4c(&sgb[m0 * 72 + nj], 72,
                                 svr[G + 1][0], svr[G + 1][1], svr[G + 1][2], svr[G + 1][3]);
                        __builtin_amdgcn_s_setprio(0);
                    }
                    barx();                            // D/F/H
                    {
                        short8 a0 = ldA(v64, 36, ln, 0, lq);
                        short8 a1 = ldA(v64, 36, ln, 1, lq);
                        floatx4 C = mf(a0, Bg[G][0], z4);
                        C = mf(a1, Bg[G][1], C);
                        float o0 = svr[G][0] * fsig(C[0]), o1 = svr[G][1] * fsig(C[1]);
                        float o2 = svr[G][2] * fsig(C[2]), o3 = svr[G][3] * fsig(C[3]);
                        st4c(&skx[m0 * 264 + G * 64 + nj], 264, o0, o1, o2, o3);
                    }
                    barx();                            // E/G/I
                }
                // J: producer finishes SD
                barx();                                    // J
                // ====== K: SG tile0 only (producer does tile1) ======
                {
                    short8 a0 = ldA(sdbb, 68, ln, 0, lq);
                    short8 a1 = ldA(sdbb, 68, ln, 1, lq);
                    short8 a2 = ldA(sdbb, 68, ln, 2, lq);
                    short8 a3 = ldA(sdbb, 68, ln, 3, lq);
                    floatx4 Ca = mf(a0, Bsg0[0], z4), Cb = mf(a1, Bsg0[1], z4);
                    Ca = mf(a2, Bsg0[2], Ca); Cb = mf(a3, Bsg0[3], Cb);
                    float u0[4];
#pragma unroll
                    for (int r = 0; r < 4; ++r)
                        u0[r] = bf2f(sdbb[(m0 + r) * 136 + n0]) * fsig(Ca[r] + Cb[r]);
                    st4c(&sobb[m0 * 136 + n0], 136, u0[0], u0[1], u0[2], u0[3]);
                }
                barx();                                    // K
                // ====== L: OUT (tanh) + state staging + global store ======
                {
                    short8 a0 = ldA(sobb, 68, ln, 0, lq);
                    short8 a1 = ldA(sobb, 68, ln, 1, lq);
                    short8 a2 = ldA(sobb, 68, ln, 2, lq);
                    short8 a3 = ldA(sobb, 68, ln, 3, lq);
                    floatx4 Ca = mf(a0, Bout[0], z4), Cb = mf(a1, Bout[1], z4);
                    Ca = mf(a2, Bout[2], Ca); Cb = mf(a3, Bout[3], Cb);
                    float ov[4];
#pragma unroll
                    for (int r = 0; r < 4; ++r) ov[r] = ftanh(Ca[r] + Cb[r]);
                    unsigned int q01 = cvtpk(ov[0], ov[1]), q23 = cvtpk(ov[2], ov[3]);
                    unsigned short ob[4] = {(unsigned short)q01, (unsigned short)(q01 >> 16),
                                            (unsigned short)q23, (unsigned short)(q23 >> 16)};
                    int hc = (base + nj) & 511;
#pragma unroll
                    for (int r = 0; r < 4; ++r) {
                        int m = m0 + r;
                        hist[m * HSTR + hc] = ob[r];
                        psb [m * 72 + nj]   = ob[r];
                        if (f32) ((float*)outp)[oi[r]] = ov[r];
                        else     ((unsigned short*)outp)[oi[r]] = ob[r];
                        oi[r] += SS;
                    }
                    st4c(&sgb[m0 * 72 + nj], 72, svr[0][0], svr[0][1], svr[0][2], svr[0][3]);
                }
                barx();                                    // L
                base += SS;
            }
        }
    } else {
        // ======================= PRODUCER (waves 4-7) =======================
        const int lane = t & 63, w4 = (t >> 6) - 4;
        const int lq = lane >> 4, ln = lane & 15;
        const int n0 = 32 * w4 + ln, n1 = n0 + 16;

        // resident B-frags: FW kb0-5; GRU r,z kb2-5; h; SD-ps weights; SG tile1
        short8 BfwP[6];
        short8 BrP[3][4], BzP[3][4], BhP[3][2];
        short8 BsdPS[4];
        short8 Bsg1[4];
#pragma unroll
        for (int j = 0; j < 6; ++j)
            BfwP[j] = ldB(wbuf, OFF_FW + (w4 * 13 + j) * 64 + lane);
#pragma unroll
        for (int G = 0; G < 3; ++G) {
            const int OR = OFF_GRU(G), OZ = OR + 1536, OH = OR + 4096;
#pragma unroll
            for (int j = 0; j < 4; ++j) {
                BrP[G][j] = ldB(wbuf, OR + (w4 * 6 + 2 + j) * 64 + lane);
                BzP[G][j] = ldB(wbuf, OZ + (w4 * 6 + 2 + j) * 64 + lane);
            }
#pragma unroll
            for (int j = 0; j < 2; ++j)
                BhP[G][j] = ldB(wbuf, OH + (w4 * 2 + j) * 64 + lane);
        }
        // SD ps-segment weights (kb8,9): [n0 kb8, n1 kb8, n0 kb9, n1 kb9]
        BsdPS[0] = ldB(wbuf, OFF_SD + ((2 * w4 + 0) * 10 + 8) * 64 + lane);
        BsdPS[1] = ldB(wbuf, OFF_SD + ((2 * w4 + 1) * 10 + 8) * 64 + lane);
        BsdPS[2] = ldB(wbuf, OFF_SD + ((2 * w4 + 0) * 10 + 9) * 64 + lane);
        BsdPS[3] = ldB(wbuf, OFF_SD + ((2 * w4 + 1) * 10 + 9) * 64 + lane);
#pragma unroll
        for (int kb = 0; kb < 4; ++kb)
            Bsg1[kb] = ldB(wbuf, OFF_SG + ((2 * w4 + 1) * 4 + kb) * 64 + lane);

        int base = 0;
        for (int f = 0; f < NFRAMES; ++f) {
            for (int kk = 0; kk < NSUB; ++kk) {
                floatx4 SD00 = z4, SD01 = z4, SD10 = z4, SD11 = z4;
                short8 aps0, aps1, asg0, asg1;
                short8 W6[4], W0[4], W2[4], W4[4];

                // GRU partials (pure-reg): ps + s -> pcG
                auto grupart = [&](int G, short8 s0f, short8 s1f) {
                    floatx4 Cr = mf(aps0, BrP[G][0], z4);
                    floatx4 Cz = mf(aps0, BzP[G][0], z4);
                    Cr = mf(aps1, BrP[G][1], Cr);
                    Cz = mf(aps1, BzP[G][1], Cz);
                    floatx4 Ch = mf(s0f, BhP[G][0], z4);
                    Cr = mf(s0f, BrP[G][2], Cr);
                    Cz = mf(s0f, BzP[G][2], Cz);
                    Ch = mf(s1f, BhP[G][1], Ch);
                    Cr = mf(s1f, BrP[G][3], Cr);
                    Cz = mf(s1f, BzP[G][3], Cz);
                    *(floatx4*)&pcG[w4][lane][0][0] = Cr;
                    *(floatx4*)&pcG[w4][lane][1][0] = Cz;
                    *(floatx4*)&pcG[w4][lane][2][0] = Ch;
                };
                // SD 2-kb segment, weights in regs
                auto sdsegW = [&](int kbs, short8* W) {
                    short8 a0 = ldA(skx, 132, ln, kbs, lq);
                    short8 a1 = ldA(skx, 132, ln, kbs + 1, lq);
                    SD00 = mf(a0, W[0], SD00); SD10 = mf(a0, W[1], SD10);
                    SD01 = mf(a1, W[2], SD01); SD11 = mf(a1, W[3], SD11);
                };
                // GLOBAL weight prefetch (vmcnt): crosses barx freely, the
                // compiler waits only at first use one phase later.
                auto ldW = [&](int kb, short8* W) {
                    W[0] = ldB(wbuf, OFF_SD + ((2 * w4 + 0) * 10 + kb) * 64 + lane);
                    W[1] = ldB(wbuf, OFF_SD + ((2 * w4 + 1) * 10 + kb) * 64 + lane);
                    W[2] = ldB(wbuf, OFF_SD + ((2 * w4 + 0) * 10 + kb + 1) * 64 + lane);
                    W[3] = ldB(wbuf, OFF_SD + ((2 * w4 + 1) * 10 + kb + 1) * 64 + lane);
                };

                // ====== A: gather + ps/s loads + FW partials (kb0-5) + SD-ps ======
                {
                    __builtin_amdgcn_s_setprio(1);
                    int per = period_s[prow];
#pragma unroll
                    for (int ii = 0; ii < 5; ++ii) {
                        int i = px16 * 5 + ii;
                        if (i < 68) {
                            int idx = LPREV - per + i - 2;
                            if (idx >= LPREV) idx -= per;
                            catb[prow * 424 + 192 + i] = hist[prow * HSTR + ((base + idx) & 511)];
                        }
                    }
                    aps0 = ldA(psb, 36, ln, 0, lq);
                    aps1 = ldA(psb, 36, ln, 1, lq);
                    asg0 = ldA(sgb, 36, ln, 0, lq);
                    asg1 = ldA(sgb, 36, ln, 1, lq);
                    short8 c0 = ldA(catb, 212, ln, 0, lq);
                    short8 c1 = ldA(catb, 212, ln, 1, lq);
                    short8 c2 = ldA(catb, 212, ln, 2, lq);
                    short8 c3 = ldA(catb, 212, ln, 3, lq);
                    floatx4 C0 = mf(c0, BfwP[0], z4);
                    floatx4 C1 = mf(c1, BfwP[1], z4);
                    floatx4 C2 = mf(c2, BfwP[2], z4);
                    floatx4 C3 = mf(c3, BfwP[3], z4);
                    C0 = mf(aps0, BfwP[4], C0);
                    C1 = mf(aps1, BfwP[5], C1);
                    // SD ps segment (kb8,9), weights resident
                    SD00 = mf(aps0, BsdPS[0], SD00);
                    SD10 = mf(aps0, BsdPS[1], SD10);
                    SD01 = mf(aps1, BsdPS[2], SD01);
                    SD11 = mf(aps1, BsdPS[3], SD11);
                    floatx4 s = (C0 + C1) + (C2 + C3);
                    *(floatx4*)&pcFW[w4][lane][0] = s;
                    __builtin_amdgcn_s_setprio(0);
                }
                barx();                                    // A
                // ====== B: GRU1 partials (pure reg) ======
                grupart(0, asg0, asg1);
                barx();                                    // B
                // ====== C: issue fw-segment weight prefetch (global) ======
                ldW(6, W6);
                barx();                                    // C
                // ====== D: SD fw (kb6,7); prefetch o1 weights ======
                sdsegW(6, W6);
                ldW(0, W0);
                barx();                                    // D
                // ====== E: GRU2 partials ======
                {
                    short8 s0f = ldA(sgb, 36, ln, 0, lq);
                    short8 s1f = ldA(sgb, 36, ln, 1, lq);
                    grupart(1, s0f, s1f);
                }
                barx();                                    // E
                // ====== F: SD o1 (kb0,1); prefetch o2 weights ======
                sdsegW(0, W0);
                ldW(2, W2);
                barx();                                    // F
                // ====== G: GRU3 partials ======
                {
                    short8 s0f = ldA(sgb, 36, ln, 0, lq);
                    short8 s1f = ldA(sgb, 36, ln, 1, lq);
                    grupart(2, s0f, s1f);
                }
                barx();                                    // G
                // ====== H: SD o2 (kb2,3); prefetch o3 weights ======
                sdsegW(2, W2);
                ldW(4, W4);
                barx();                                    // H
                // ====== I: idle ======
                barx();                                    // I
                // ====== J: SD o3 (kb4,5) + tanh -> sdbb ======
                {
                    __builtin_amdgcn_s_setprio(1);
                    sdsegW(4, W4);
                    float t0[4], t1[4];
#pragma unroll
                    for (int r = 0; r < 4; ++r) {
                        t0[r] = ftanh(SD00[r] + SD01[r]);
                        t1[r] = ftanh(SD10[r] + SD11[r]);
                    }
                    st4c(&sdbb[(4 * lq) * 136 + n0], 136, t0[0], t0[1], t0[2], t0[3]);
                    st4c(&sdbb[(4 * lq) * 136 + n1], 136, t1[0], t1[1], t1[2], t1[3]);
                    __builtin_amdgcn_s_setprio(0);
                }
                barx();                                    // J
                // ====== K: SG tile1 ======
                {
                    short8 a0 = ldA(sdbb, 68, ln, 0, lq);
                    short8 a1 = ldA(sdbb, 68, ln, 1, lq);
                    short8 a2 = ldA(sdbb, 68, ln, 2, lq);
                    short8 a3 = ldA(sdbb, 68, ln, 3, lq);
                    floatx4 Cc = mf(a0, Bsg1[0], z4), Cd = mf(a1, Bsg1[1], z4);
                    Cc = mf(a2, Bsg1[2], Cc); Cd = mf(a3, Bsg1[3], Cd);
                    float u1[4];
#pragma unroll
                    for (int r = 0; r < 4; ++r)
                        u1[r] = bf2f(sdbb[(4 * lq + r) * 136 + n1]) * fsig(Cc[r] + Cd[r]);
                    st4c(&sobb[(4 * lq) * 136 + n1], 136, u1[0], u1[1], u1[2], u1[3]);
                }
                barx();                                    // K
                // ====== L: feat2s shuffle + prefetch + period ======
                {
                    unsigned int* cat32 = (unsigned int*)catb;
                    int cb = prow * 212;
                    int u0 = pe8 >> 1;
                    unsigned int o0 = cat32[cb + u0 + 0];
                    unsigned int o1 = cat32[cb + u0 + 1];
                    unsigned int o2 = cat32[cb + u0 + 2];
                    unsigned int o3 = cat32[cb + u0 + 3];
                    cat32[cb + 130 + u0 + 0] = o0;
                    cat32[cb + 130 + u0 + 1] = o1;
                    cat32[cb + 130 + u0 + 2] = o2;
                    cat32[cb + 130 + u0 + 3] = o3;
                    *(uint4*)(cat32 + cb + u0) = pfc;
                    int sN = f * 4 + kk + 2;
                    if (sN > NFRAMES * 4 - 1) sN = NFRAMES * 4 - 1;
                    pfc = *(const uint4*)(cb16
                        + ((size_t)(b0 + prow) * NFRAMES + (sN >> 2)) * 512 + (sN & 3) * 128 + pe8);
                    if (kk == 0 && t < 256 + RPW) {
                        int fN = (f + 1 < NFRAMES) ? f + 1 : f;
                        pper = ld1f(f32, feats,
                                    (size_t)(b0 + (t - 256)) * (NF * NFRAMES) + (NF - 1) * NFRAMES + fN);
                    }
                    if (kk == 3 && t < 256 + RPW) period_s[t - 256] = (int)rintf(pper);
                }
                barx();                                    // L
                base += SS;
            }
        }
    }
}

// ---------- launch ----------
extern "C" void kernel_launch(void* const* d_in, const int* in_sizes, int n_in,
                              void* d_out, int out_size, void* d_ws, size_t ws_size,
                              hipStream_t stream) {
    const void* feats = d_in[0];
    const void* gfeat = d_in[1];
    const void* prev  = d_in[2];
    const void* Wc1   = d_in[3];
    const void* Wc2   = d_in[4];
    const void* Wc3   = d_in[5];
    const void* Wfw   = d_in[6];
    const void* Wfwg  = d_in[7];
    const void* Wih1  = d_in[8];
    const void* Whh1  = d_in[9];
    const void* Wih2  = d_in[10];
    const void* Whh2  = d_in[11];
    const void* Wih3  = d_in[12];
    const void* Whh3  = d_in[13];
    const void* Wg1   = d_in[14];
    const void* Wg2   = d_in[15];
    const void* Wg3   = d_in[16];
    const void* Wsg   = d_in[17];
    const void* Wsd   = d_in[18];
    const void* Wout  = d_in[19];

    int*            flag = (int*)d_ws;                                      // @0
    unsigned short* cb16 = (unsigned short*)((char*)d_ws + 256);            // 6,553,600 B
    unsigned int*   wct  = (unsigned int*)((char*)d_ws + 256 + 6553600);    // 524,288 B
    uint4*          wbuf = (uint4*)((char*)d_ws + 256 + 6553600 + 524288);  // 438,272 B

    fargan_detect<<<1, 1, 0, stream>>>(feats, flag);
    fargan_prep<<<(NFRAG + 255) / 256, 256, 0, stream>>>(flag, Wfw, Wfwg,
        Wih1, Whh1, Wih2, Whh2, Wih3, Whh3, Wg1, Wg2, Wg3, Wsg, Wsd, Wout, wbuf);
    fargan_prep_conv<<<512, 256, 0, stream>>>(flag, Wc1, Wc2, Wc3, wct);
    fargan_conv<<<BATCH * 25, 256, 0, stream>>>(feats, gfeat, flag, wct, cb16);
    fargan_seq<<<BATCH / RPW, 512, 0, stream>>>(feats, prev, flag, cb16, wbuf, d_out);
}

// Round 10
// 1944.780 us; speedup vs baseline: 11.8117x; 1.1447x over previous
//
#include <hip/hip_runtime.h>
#include <hip/hip_bf16.h>

// FARGAN vocoder on MI355X. Sizes fixed by the reference:
#define SS      64
#define NSUB    4
#define LPREV   512
#define NF      193
#define NFRAMES 100
#define BATCH   64
#define RPW     16     // batch rows per workgroup (MFMA M)
#define HSTR    514    // hist row stride (u16); odd u32 stride -> bank stagger

typedef __attribute__((ext_vector_type(8))) short   short8;   // 8 bf16 (4 VGPRs)
typedef __attribute__((ext_vector_type(4))) float   floatx4;  // MFMA C/D

// ---------- scalar helpers ----------
__device__ __forceinline__ float bf2f(unsigned short u) {
    return __uint_as_float(((unsigned int)u) << 16);
}
__device__ __forceinline__ unsigned short f2bf(float x) {
    unsigned int u = __float_as_uint(x);
    return (unsigned short)((u + 0x7fffu + ((u >> 16) & 1u)) >> 16);
}
__device__ __forceinline__ unsigned int packbf(float a, float b) {
    return (unsigned int)f2bf(a) | ((unsigned int)f2bf(b) << 16);
}
__device__ __forceinline__ float fexp2(float x) {
#if __has_builtin(__builtin_amdgcn_exp2f)
    return __builtin_amdgcn_exp2f(x);
#else
    return exp2f(x);
#endif
}
__device__ __forceinline__ float frcp(float x) {
#if __has_builtin(__builtin_amdgcn_rcpf)
    return __builtin_amdgcn_rcpf(x);
#else
    return 1.0f / x;
#endif
}
__device__ __forceinline__ float fsig(float x) {
    return frcp(1.0f + fexp2(-1.442695041f * x));
}
__device__ __forceinline__ float ftanh(float x) {
    return fmaf(2.0f, frcp(1.0f + fexp2(-2.885390082f * x)), -1.0f);
}
__device__ __forceinline__ float ld1f(int f32, const void* p, size_t i) {
    if (f32) return ((const float*)p)[i];
    return bf2f(((const unsigned short*)p)[i]);
}
__device__ __forceinline__ float lo16(unsigned int u) { return __uint_as_float(u << 16); }
__device__ __forceinline__ float hi16(unsigned int u) { return __uint_as_float(u & 0xffff0000u); }

// packed f32->bf16 RNE conversion (1 instr / 2 values)
__device__ __forceinline__ unsigned int cvtpk(float lo, float hi) {
    unsigned int r;
    asm("v_cvt_pk_bf16_f32 %0, %1, %2" : "=v"(r) : "v"(lo), "v"(hi));
    return r;
}
// store 4 values down a column (rows +0..+3): 2 cvt_pk + 4 b16 stores
__device__ __forceinline__ void st4c(unsigned short* p, int strideU16,
                                     float a, float b, float c, float d) {
    unsigned int p01 = cvtpk(a, b), p23 = cvtpk(c, d);
    p[0]             = (unsigned short)p01;
    p[strideU16]     = (unsigned short)(p01 >> 16);
    p[2 * strideU16] = (unsigned short)p23;
    p[3 * strideU16] = (unsigned short)(p23 >> 16);
}

// MFMA wrapper
__device__ __forceinline__ floatx4 mf(short8 a, short8 b, floatx4 c) {
    return __builtin_amdgcn_mfma_f32_16x16x32_bf16(a, b, c, 0, 0, 0);
}

// A-fragment from packed-bf16 LDS buffer: row m, k-block kb, quad q. strideU in u32.
__device__ __forceinline__ short8 ldA(const unsigned short* buf, int strideU,
                                      int m, int kb, int q) {
    const unsigned int* p = (const unsigned int*)buf + m * strideU + kb * 16 + q * 4;
    uint4 u = *(const uint4*)p;
    return __builtin_bit_cast(short8, u);
}
// B-fragment from prepacked weight buffer
__device__ __forceinline__ short8 ldB(const uint4* __restrict__ w, int idx) {
    return __builtin_bit_cast(short8, w[idx]);
}

// lgkm-only barrier: do NOT drain vmcnt (prefetch loads + output stores stay
// in flight). Memory clobbers keep the compiler from moving LDS ops across.
__device__ __forceinline__ void barx() {
    asm volatile("s_waitcnt lgkmcnt(0)" ::: "memory");
    __builtin_amdgcn_s_barrier();
    asm volatile("" ::: "memory");
}

// ---------- wbuf layout (units = 16B frags) ----------
#define OFF_FW   0        // 4t x 13kb
#define OFF_FWG  3328     // 4t x 2kb
#define OFF_GRU(G) (3840 + 4608*(G))   // r@+0(6kb) z@+1536(6kb) i@+3072(4kb) h@+4096(2kb)
#define OFF_WG(G)  (17664 + 512*(G))   // 4t x 2kb
#define OFF_SD   19200    // 8t x 10kb
#define OFF_SG   24320    // 8t x 4kb
#define OFF_OUT  26368    // 4t x 4kb
#define NFRAG    27392

// ---------- dtype detector ----------
__global__ void fargan_detect(const void* feats, int* flag) {
    const float* pf = (const float*)feats;
    int ok = 1;
    for (int f = 0; f < 50; ++f) {
        float v = pf[192 * NFRAMES + f];
        if (!(v >= 63.0f && v <= 301.0f)) { ok = 0; break; }
    }
    *flag = ok;
}

// ---------- weight prep: repack all seq weights into frag order ----------
__global__ __launch_bounds__(256) void fargan_prep(
    const int* __restrict__ flag,
    const void* Wfw, const void* Wfwg,
    const void* Wih1, const void* Whh1, const void* Wih2, const void* Whh2,
    const void* Wih3, const void* Whh3,
    const void* Wg1, const void* Wg2, const void* Wg3,
    const void* Wsg, const void* Wsd, const void* Wout,
    uint4* __restrict__ wbuf)
{
    int fi = blockIdx.x * 256 + threadIdx.x;
    if (fi >= NFRAG) return;
    int f32 = *flag;
    const void* mats[14] = {Wfw, Wfwg, Wih1, Whh1, Wih2, Whh2, Wih3, Whh3,
                            Wg1, Wg2, Wg3, Wsg, Wsd, Wout};
    const int NSEG = 20;
    const int sb[NSEG]  = {0,3328, 3840,5376,6912,7936, 8448,9984,11520,12544,
                           13056,14592,16128,17152, 17664,18176,18688, 19200,24320,26368};
    const int sa[NSEG]  = {0,1, 2,2,2,3, 4,4,4,5, 6,6,6,7, 8,9,10, 12,11,13};
    const int sbx[NSEG] = {-1,-1, 3,3,-1,-1, 5,5,-1,-1, 7,7,-1,-1, -1,-1,-1, -1,-1,-1};
    const int sro[NSEG] = {0,0, 0,64,128,128, 0,64,128,128, 0,64,128,128, 0,0,0, 0,0,0};
    const int skb[NSEG] = {13,2, 6,6,4,2, 6,6,4,2, 6,6,4,2, 2,2,2, 10,4,4};
    const int ska[NSEG] = {388,64, 128,128,128,64, 128,128,128,64, 128,128,128,64,
                           64,64,64, 320,128,128};
    const int skr[NSEG] = {388,64, 192,192,128,64, 192,192,128,64, 192,192,128,64,
                           64,64,64, 320,128,128};
    int s = 0;
    for (int i = 1; i < NSEG; ++i) if (fi >= sb[i]) s = i;
    int local = fi - sb[s];
    int ln = local & 15, lq = (local >> 4) & 3, tkb = local >> 6;
    int KB = skb[s];
    int kb = tkb % KB, tile = tkb / KB;
    int row = sro[s] + tile * 16 + ln;
    int Ka = ska[s], Kr = skr[s];
    union { unsigned short h[8]; uint4 v; } u;
#pragma unroll
    for (int j = 0; j < 8; ++j) {
        int k = kb * 32 + lq * 8 + j;
        unsigned short val = 0;
        if (k < Kr) {
            const void* m; size_t off;
            if (sbx[s] >= 0 && k >= Ka) { m = mats[sbx[s]]; off = (size_t)row * 64 + (k - Ka); }
            else                        { m = mats[sa[s]];  off = (size_t)row * Ka + k; }
            val = f32 ? f2bf(((const float*)m)[off]) : ((const unsigned short*)m)[off];
        }
        u.h[j] = val;
    }
    wbuf[fi] = u.v;
}

// ---------- prep: repack Wc1/2/3 transposed + bf16-pair packed ----------
__global__ __launch_bounds__(256) void fargan_prep_conv(
    const int* __restrict__ flag,
    const void* Wc1, const void* Wc2, const void* Wc3,
    unsigned int* __restrict__ wct)
{
    int idx = blockIdx.x * 256 + threadIdx.x;
    if (idx >= 131072) return;
    int f32 = *flag;
    const void* W; int n, k2;
    if (idx < 32768)      { W = Wc1; k2 = idx >> 8, n = idx & 255; }
    else if (idx < 65536) { W = Wc2; k2 = (idx - 32768) >> 8; n = idx & 255; }
    else                  { W = Wc3; k2 = (idx - 65536) >> 9; n = (idx - 65536) & 511; }
    size_t off = (size_t)n * 256 + 2 * k2;
    unsigned int v;
    if (f32) {
        const float* p = (const float*)W + off;
        v = packbf(p[0], p[1]);
    } else {
        v = *(const unsigned int*)((const unsigned short*)W + off);
    }
    wct[idx] = v;
}

// ---------- kernel 1: frame conv -> bf16 output cb16[b][f][k*128+j] ----------
template<bool F32>
__device__ __forceinline__ void conv_body(
    const void* __restrict__ feats, const void* __restrict__ gfeat,
    const unsigned int* __restrict__ wct, unsigned short* __restrict__ cb16)
{
    int blk = blockIdx.x;
    int b = blk / 25, fq = blk - b * 25;
    int f0 = fq * 4;
    int t = threadIdx.x;
    __shared__ float xa[4][256], xb[4][256];

#pragma unroll
    for (int j = 0; j < 4; ++j) {
        float v;
        if (t < 192) v = ld1f(F32 ? 1 : 0, feats, (size_t)b * (NF * NFRAMES) + t * NFRAMES + f0 + j);
        else         v = ld1f(F32 ? 1 : 0, gfeat, (size_t)b * 64 + (t - 192));
        xa[j][t] = v;
    }
    __syncthreads();

    const unsigned int* w1 = wct;
    const unsigned int* w2 = wct + 32768;
    const unsigned int* w3 = wct + 65536;

    float a0[4], a1[4], b0[4], b1[4];
#pragma unroll
    for (int j = 0; j < 4; ++j) { a0[j] = 0.f; a1[j] = 0.f; }
#pragma unroll 4
    for (int k2 = 0; k2 < 128; ++k2) {
        unsigned int u = w1[k2 * 256 + t];
        float lo = lo16(u), hi = hi16(u);
#pragma unroll
        for (int j = 0; j < 4; ++j) {
            a0[j] = fmaf(lo, xa[j][2 * k2], a0[j]);
            a1[j] = fmaf(hi, xa[j][2 * k2 + 1], a1[j]);
        }
    }
#pragma unroll
    for (int j = 0; j < 4; ++j) xb[j][t] = ftanh(a0[j] + a1[j]);
    __syncthreads();

#pragma unroll
    for (int j = 0; j < 4; ++j) { a0[j] = 0.f; a1[j] = 0.f; }
#pragma unroll 4
    for (int k2 = 0; k2 < 128; ++k2) {
        unsigned int u = w2[k2 * 256 + t];
        float lo = lo16(u), hi = hi16(u);
#pragma unroll
        for (int j = 0; j < 4; ++j) {
            a0[j] = fmaf(lo, xb[j][2 * k2], a0[j]);
            a1[j] = fmaf(hi, xb[j][2 * k2 + 1], a1[j]);
        }
    }
    __syncthreads();
#pragma unroll
    for (int j = 0; j < 4; ++j) xa[j][t] = ftanh(a0[j] + a1[j]);
    __syncthreads();

#pragma unroll
    for (int j = 0; j < 4; ++j) { a0[j] = 0.f; a1[j] = 0.f; b0[j] = 0.f; b1[j] = 0.f; }
#pragma unroll 4
    for (int k2 = 0; k2 < 128; ++k2) {
        unsigned int u  = w3[k2 * 512 + t];
        unsigned int u2 = w3[k2 * 512 + t + 256];
        float lo = lo16(u), hi = hi16(u), lo2 = lo16(u2), hi2 = hi16(u2);
#pragma unroll
        for (int j = 0; j < 4; ++j) {
            a0[j] = fmaf(lo,  xa[j][2 * k2],     a0[j]);
            a1[j] = fmaf(hi,  xa[j][2 * k2 + 1], a1[j]);
            b0[j] = fmaf(lo2, xa[j][2 * k2],     b0[j]);
            b1[j] = fmaf(hi2, xa[j][2 * k2 + 1], b1[j]);
        }
    }
    int e0 = t, e1 = t + 256;
#pragma unroll
    for (int j = 0; j < 4; ++j) {
        unsigned short* co = cb16 + ((size_t)b * NFRAMES + f0 + j) * 512;
        co[(e0 & 3) * 128 + (e0 >> 2)] = f2bf(ftanh(a0[j] + a1[j]));
        co[(e1 & 3) * 128 + (e1 >> 2)] = f2bf(ftanh(b0[j] + b1[j]));
    }
}

__global__ __launch_bounds__(256) void fargan_conv(
    const void* feats, const void* gfeat,
    const int* flag, const unsigned int* wct, unsigned short* cb16)
{
    if (*flag) conv_body<true>(feats, gfeat, wct, cb16);
    else       conv_body<false>(feats, gfeat, wct, cb16);
}

// ---------- kernel 2: sequential recurrence ----------
// BEST-MEASURED STRUCTURE (seq ~1758 us). Producer/consumer wave
// specialization, 8 waves (2/SIMD): consumer finishes each layer + all
// elementwise; producer computes phase-early partial K-segments (FW kb0-5,
// GRU ps+state segments, SD), handing off via f32 LDS buffers one barrier
// ahead. 12 lgkm-only barriers per subframe step (structural floor for this
// decomposition: 12 serial layers x cross-wave exchange per layer).
// Verified-neutral additions kept: phase rebalance (FW sfw->consumer A, SG
// n-tile split), per-phase s_setprio, pointer-incremented output stores.

__global__ __launch_bounds__(512) __attribute__((amdgpu_waves_per_eu(2, 2)))
void fargan_seq(
    const void* __restrict__ feats, const void* __restrict__ prev_in,
    const int* __restrict__ flag, const unsigned short* __restrict__ cb16,
    const uint4* __restrict__ wbuf, void* __restrict__ outp)
{
    const int t = threadIdx.x;
    const int b0 = blockIdx.x * RPW;
    const int f32 = *flag;

    // ---- LDS (~151 KB) ----
    __shared__ __align__(16) unsigned short hist[RPW * HSTR];  // bf16 ring, mod-512
    __shared__ __align__(16) unsigned short catb[RPW * 424];   // [feat2s|ps|look|sfw|pad]
    __shared__ __align__(16) unsigned short psb [RPW * 72];    // prev_sub (once)
    __shared__ __align__(16) unsigned short sgb [RPW * 72];    // staged GRU state
    __shared__ __align__(16) unsigned short skx [RPW * 264];   // [o1|o2|o3|fw]
    __shared__ __align__(16) unsigned short sdbb[RPW * 136];
    __shared__ __align__(16) unsigned short sobb[RPW * 136];
    __shared__ __align__(16) unsigned short v64 [RPW * 72];
    __shared__ __align__(16) unsigned short wsd[128 * 328];    // Wsd, 164u stride
    __shared__ __align__(16) float pcFW[4][64][4];             // FW partial (P->C)
    __shared__ __align__(16) float pcG [4][64][3][4];          // GRU partials r,z,h
    __shared__ int period_s[RPW];

    // ---- Wsd -> LDS from wbuf (512 threads) ----
    for (int fi = t; fi < 8 * 10 * 64; fi += 512) {
        int lane2 = fi & 63, tkb = fi >> 6;
        int kb = tkb % 10, tile = tkb / 10;
        int lq2 = lane2 >> 4, ln2 = lane2 & 15;
        int row = tile * 16 + ln2;
        uint4 v = wbuf[OFF_SD + fi];
        *(uint4*)((unsigned int*)wsd + row * 164 + kb * 16 + lq2 * 4) = v;
    }

    // ---- zero init LDS state + hist fill ----
    for (int i = t; i < RPW * 424; i += 512) catb[i] = 0;
    for (int i = t; i < RPW * 72;  i += 512) { psb[i] = 0; sgb[i] = 0; v64[i] = 0; }
    for (int i = t; i < RPW * 264; i += 512) skx[i] = 0;
    for (int i = t; i < RPW * 136; i += 512) { sdbb[i] = 0; sobb[i] = 0; }
    for (int i = t; i < RPW * 512; i += 512) {
        int row = i >> 9, c = i & 511;
        hist[row * HSTR + c] = f2bf(ld1f(f32, prev_in, (size_t)(b0 + row) * LPREV + c));
    }
    __syncthreads();
    // initial prev_sub (step 0): window[448..511] of prev_in -> psb
    for (int i = t; i < RPW * 64; i += 512) {
        int row = i >> 6, c = i & 63;
        psb[row * 72 + c] = hist[row * HSTR + 448 + c];
    }

    // producer staging mapping (threads 256..511: 16 threads/row, 8 bf16 each)
    const int prow = (t & 255) >> 4, px16 = t & 15, pe8 = (t & 15) * 8;
    uint4 pfc = {0, 0, 0, 0};
    float pper = 0.f;
    if (t >= 256) {
        // feat2s(step 0) synchronous write; prefetch feat2s(step 1)
        uint4 u0 = *(const uint4*)(cb16 + ((size_t)(b0 + prow) * NFRAMES + 0) * 512 + 0 * 128 + pe8);
        *(uint4*)((unsigned int*)catb + prow * 212 + (pe8 >> 1)) = u0;
        pfc = *(const uint4*)(cb16 + ((size_t)(b0 + prow) * NFRAMES + 0) * 512 + 1 * 128 + pe8);
        if (t < 256 + RPW) {
            pper = ld1f(f32, feats, (size_t)(b0 + (t - 256)) * (NF * NFRAMES) + (NF - 1) * NFRAMES + 0);
            period_s[t - 256] = (int)rintf(pper);
        }
    }
    __syncthreads();

    const floatx4 z4 = {0.f, 0.f, 0.f, 0.f};

    if (t < 256) {
        // ======================= CONSUMER (waves 0-3) =======================
        const int lane = t & 63, w = t >> 6;
        const int lq = lane >> 4, ln = lane & 15;
        const int nj = 16 * w + ln;
        const int n0 = 32 * w + ln, n1 = n0 + 16;
        const int m0 = 4 * lq;

        // resident B-frags: FW kb6-8 (finish) + kb9-12 (sfw, phase A)
        short8 BfwC[3], BfwA[4], Bfwg[2], Bout[4];
        short8 BrC[3][2], BzC[3][2], BiC[3][4], Bg[3][2];
        short8 Bsg0[4];                                   // SG tile0 only
#pragma unroll
        for (int j = 0; j < 3; ++j) BfwC[j] = ldB(wbuf, OFF_FW + (w * 13 + 6 + j) * 64 + lane);
#pragma unroll
        for (int j = 0; j < 4; ++j) BfwA[j] = ldB(wbuf, OFF_FW + (w * 13 + 9 + j) * 64 + lane);
#pragma unroll
        for (int kb = 0; kb < 2; ++kb) Bfwg[kb] = ldB(wbuf, OFF_FWG + (w * 2 + kb) * 64 + lane);
#pragma unroll
        for (int G = 0; G < 3; ++G) {
            const int OR = OFF_GRU(G), OZ = OR + 1536, OI = OR + 3072;
#pragma unroll
            for (int kb = 0; kb < 2; ++kb) {
                BrC[G][kb] = ldB(wbuf, OR + (w * 6 + kb) * 64 + lane);
                BzC[G][kb] = ldB(wbuf, OZ + (w * 6 + kb) * 64 + lane);
                Bg[G][kb]  = ldB(wbuf, OFF_WG(G) + (w * 2 + kb) * 64 + lane);
            }
#pragma unroll
            for (int kb = 0; kb < 4; ++kb) BiC[G][kb] = ldB(wbuf, OI + (w * 4 + kb) * 64 + lane);
        }
#pragma unroll
        for (int kb = 0; kb < 4; ++kb)
            Bsg0[kb] = ldB(wbuf, OFF_SG + ((2 * w + 0) * 4 + kb) * 64 + lane);
#pragma unroll
        for (int kb = 0; kb < 4; ++kb) Bout[kb] = ldB(wbuf, OFF_OUT + (w * 4 + kb) * 64 + lane);

        floatx4 svr[3];
#pragma unroll
        for (int G = 0; G < 3; ++G) svr[G] = z4;

        // pointer-incremented output indices (one per r)
        size_t oi[4];
#pragma unroll
        for (int r = 0; r < 4; ++r)
            oi[r] = (size_t)(b0 + m0 + r) * (NFRAMES * NSUB * SS) + nj;

        int base = 0;
        for (int f = 0; f < NFRAMES; ++f) {
            for (int kk = 0; kk < NSUB; ++kk) {
                // ====== A: FW sfw segment (kb9-12) + step-constant ps preload ======
                floatx4 C0 = z4, C1 = z4, C2 = z4, C3 = z4;
                short8 cps0 = ldA(psb, 36, ln, 0, lq);
                short8 cps1 = ldA(psb, 36, ln, 1, lq);
                {
                    short8 c9 = ldA(catb, 212, ln,  9, lq);
                    short8 cA = ldA(catb, 212, ln, 10, lq);
                    short8 cB = ldA(catb, 212, ln, 11, lq);
                    short8 cC = ldA(catb, 212, ln, 12, lq);
                    C2 = mf(c9, BfwA[0], C2);
                    C3 = mf(cA, BfwA[1], C3);
                    C0 = mf(cB, BfwA[2], C0);
                    C1 = mf(cC, BfwA[3], C1);
                }
                barx();                                    // A
                // ====== B: FW finish (kb6-8) + producer partial + tanh -> v64 ======
                float xr[4];
                {
                    __builtin_amdgcn_s_setprio(1);
                    short8 a6 = ldA(catb, 212, ln, 6, lq);
                    short8 a7 = ldA(catb, 212, ln, 7, lq);
                    short8 a8 = ldA(catb, 212, ln, 8, lq);
                    floatx4 pf = *(const floatx4*)&pcFW[w][lane][0];
                    C0 = mf(a6, BfwC[0], C0);
                    C1 = mf(a7, BfwC[1], C1);
                    C2 = mf(a8, BfwC[2], C2);
#pragma unroll
                    for (int r = 0; r < 4; ++r)
                        xr[r] = ftanh((C0[r] + C1[r]) + (C2[r] + C3[r] + pf[r]));
                    st4c(&v64[m0 * 72 + nj], 72, xr[0], xr[1], xr[2], xr[3]);
                    __builtin_amdgcn_s_setprio(0);
                }
                barx();                                    // B
                // ====== C: FWG glu -> skx fw ======
                {
                    short8 a0 = ldA(v64, 36, ln, 0, lq);
                    short8 a1 = ldA(v64, 36, ln, 1, lq);
                    floatx4 C = mf(a0, Bfwg[0], z4);
                    C = mf(a1, Bfwg[1], C);
                    float o0 = xr[0] * fsig(C[0]), o1 = xr[1] * fsig(C[1]);
                    float o2 = xr[2] * fsig(C[2]), o3 = xr[3] * fsig(C[3]);
                    st4c(&skx[m0 * 264 + 192 + nj], 264, o0, o1, o2, o3);
                }
                barx();                                    // C
                // ====== GRU finish + GLU x3 ======
#pragma unroll
                for (int G = 0; G < 3; ++G) {
                    {
                        __builtin_amdgcn_s_setprio(1);
                        const int inkb = (G == 0) ? 6 : (G == 1) ? 0 : 2;
                        short8 a0 = ldA(skx, 132, ln, inkb, lq);
                        short8 a1 = ldA(skx, 132, ln, inkb + 1, lq);
                        floatx4 pr = *(const floatx4*)&pcG[w][lane][0][0];
                        floatx4 pz = *(const floatx4*)&pcG[w][lane][1][0];
                        floatx4 ph = *(const floatx4*)&pcG[w][lane][2][0];
                        floatx4 Ci = mf(cps0, BiC[G][2], z4);
                        Ci = mf(cps1, BiC[G][3], Ci);
                        floatx4 Cr = mf(a0, BrC[G][0], z4);
                        floatx4 Cz = mf(a0, BzC[G][0], z4);
                        Ci = mf(a0, BiC[G][0], Ci);
                        Cr = mf(a1, BrC[G][1], Cr);
                        Cz = mf(a1, BzC[G][1], Cz);
                        Ci = mf(a1, BiC[G][1], Ci);
                        float sn[4];
#pragma unroll
                        for (int r = 0; r < 4; ++r) {
                            float rr = fsig(Cr[r] + pr[r]);
                            float zz = fsig(Cz[r] + pz[r]);
                            float nn = ftanh(Ci[r] + rr * ph[r]);
                            sn[r] = fmaf(zz, svr[G][r] - nn, nn);
                            svr[G][r] = sn[r];
                        }
                        st4c(&v64[m0 * 72 + nj], 72, sn[0], sn[1], sn[2], sn[3]);
                        if (G < 2)
                            st4c(&sgb[m0 * 72 + nj], 72,
                                 svr[G + 1][0], svr[G + 1][1], svr[G + 1][2], svr[G + 1][3]);
                        __builtin_amdgcn_s_setprio(0);
                    }
                    barx();                            // D/F/H
                    {
                        short8 a0 = ldA(v64, 36, ln, 0, lq);
                        short8 a1 = ldA(v64, 36, ln, 1, lq);
                        floatx4 C = mf(a0, Bg[G][0], z4);
                        C = mf(a1, Bg[G][1], C);
                        float o0 = svr[G][0] * fsig(C[0]), o1 = svr[G][1] * fsig(C[1]);
                        float o2 = svr[G][2] * fsig(C[2]), o3 = svr[G][3] * fsig(C[3]);
                        st4c(&skx[m0 * 264 + G * 64 + nj], 264, o0, o1, o2, o3);
                    }
                    barx();                            // E/G/I
                }
                // J: producer finishes SD
                barx();                                    // J
                // ====== K: SG tile0 only (producer does tile1) ======
                {
                    short8 a0 = ldA(sdbb, 68, ln, 0, lq);
                    short8 a1 = ldA(sdbb, 68, ln, 1, lq);
                    short8 a2 = ldA(sdbb, 68, ln, 2, lq);
                    short8 a3 = ldA(sdbb, 68, ln, 3, lq);
                    floatx4 Ca = mf(a0, Bsg0[0], z4), Cb = mf(a1, Bsg0[1], z4);
                    Ca = mf(a2, Bsg0[2], Ca); Cb = mf(a3, Bsg0[3], Cb);
                    float u0[4];
#pragma unroll
                    for (int r = 0; r < 4; ++r)
                        u0[r] = bf2f(sdbb[(m0 + r) * 136 + n0]) * fsig(Ca[r] + Cb[r]);
                    st4c(&sobb[m0 * 136 + n0], 136, u0[0], u0[1], u0[2], u0[3]);
                }
                barx();                                    // K
                // ====== L: OUT (tanh) + state staging + global store ======
                {
                    short8 a0 = ldA(sobb, 68, ln, 0, lq);
                    short8 a1 = ldA(sobb, 68, ln, 1, lq);
                    short8 a2 = ldA(sobb, 68, ln, 2, lq);
                    short8 a3 = ldA(sobb, 68, ln, 3, lq);
                    floatx4 Ca = mf(a0, Bout[0], z4), Cb = mf(a1, Bout[1], z4);
                    Ca = mf(a2, Bout[2], Ca); Cb = mf(a3, Bout[3], Cb);
                    float ov[4];
#pragma unroll
                    for (int r = 0; r < 4; ++r) ov[r] = ftanh(Ca[r] + Cb[r]);
                    unsigned int q01 = cvtpk(ov[0], ov[1]), q23 = cvtpk(ov[2], ov[3]);
                    unsigned short ob[4] = {(unsigned short)q01, (unsigned short)(q01 >> 16),
                                            (unsigned short)q23, (unsigned short)(q23 >> 16)};
                    int hc = (base + nj) & 511;
#pragma unroll
                    for (int r = 0; r < 4; ++r) {
                        int m = m0 + r;
                        hist[m * HSTR + hc] = ob[r];
                        psb [m * 72 + nj]   = ob[r];
                        if (f32) ((float*)outp)[oi[r]] = ov[r];
                        else     ((unsigned short*)outp)[oi[r]] = ob[r];
                        oi[r] += SS;
                    }
                    st4c(&sgb[m0 * 72 + nj], 72, svr[0][0], svr[0][1], svr[0][2], svr[0][3]);
                }
                barx();                                    // L
                base += SS;
            }
        }
    } else {
        // ======================= PRODUCER (waves 4-7) =======================
        const int lane = t & 63, w4 = (t >> 6) - 4;
        const int lq = lane >> 4, ln = lane & 15;
        const int n0 = 32 * w4 + ln, n1 = n0 + 16;

        // resident B-frags: FW kb0-5; GRU r,z kb2-5; h; SD-ps weights; SG tile1
        short8 BfwP[6];
        short8 BrP[3][4], BzP[3][4], BhP[3][2];
        short8 BsdPS[4];
        short8 Bsg1[4];
#pragma unroll
        for (int j = 0; j < 6; ++j)
            BfwP[j] = ldB(wbuf, OFF_FW + (w4 * 13 + j) * 64 + lane);
#pragma unroll
        for (int G = 0; G < 3; ++G) {
            const int OR = OFF_GRU(G), OZ = OR + 1536, OH = OR + 4096;
#pragma unroll
            for (int j = 0; j < 4; ++j) {
                BrP[G][j] = ldB(wbuf, OR + (w4 * 6 + 2 + j) * 64 + lane);
                BzP[G][j] = ldB(wbuf, OZ + (w4 * 6 + 2 + j) * 64 + lane);
            }
#pragma unroll
            for (int j = 0; j < 2; ++j)
                BhP[G][j] = ldB(wbuf, OH + (w4 * 2 + j) * 64 + lane);
        }
        // SD ps-segment weights (kb8,9): [n0 kb8, n1 kb8, n0 kb9, n1 kb9]
        BsdPS[0] = ldB(wbuf, OFF_SD + ((2 * w4 + 0) * 10 + 8) * 64 + lane);
        BsdPS[1] = ldB(wbuf, OFF_SD + ((2 * w4 + 1) * 10 + 8) * 64 + lane);
        BsdPS[2] = ldB(wbuf, OFF_SD + ((2 * w4 + 0) * 10 + 9) * 64 + lane);
        BsdPS[3] = ldB(wbuf, OFF_SD + ((2 * w4 + 1) * 10 + 9) * 64 + lane);
#pragma unroll
        for (int kb = 0; kb < 4; ++kb)
            Bsg1[kb] = ldB(wbuf, OFF_SG + ((2 * w4 + 1) * 4 + kb) * 64 + lane);

        int base = 0;
        for (int f = 0; f < NFRAMES; ++f) {
            for (int kk = 0; kk < NSUB; ++kk) {
                floatx4 SD00 = z4, SD01 = z4, SD10 = z4, SD11 = z4;
                short8 aps0, aps1, asg0, asg1;
                short8 W6[4], W0[4], W2[4], W4[4];

                // GRU partials (pure-reg): ps + s -> pcG
                auto grupart = [&](int G, short8 s0f, short8 s1f) {
                    floatx4 Cr = mf(aps0, BrP[G][0], z4);
                    floatx4 Cz = mf(aps0, BzP[G][0], z4);
                    Cr = mf(aps1, BrP[G][1], Cr);
                    Cz = mf(aps1, BzP[G][1], Cz);
                    floatx4 Ch = mf(s0f, BhP[G][0], z4);
                    Cr = mf(s0f, BrP[G][2], Cr);
                    Cz = mf(s0f, BzP[G][2], Cz);
                    Ch = mf(s1f, BhP[G][1], Ch);
                    Cr = mf(s1f, BrP[G][3], Cr);
                    Cz = mf(s1f, BzP[G][3], Cz);
                    *(floatx4*)&pcG[w4][lane][0][0] = Cr;
                    *(floatx4*)&pcG[w4][lane][1][0] = Cz;
                    *(floatx4*)&pcG[w4][lane][2][0] = Ch;
                };
                // SD 2-kb segment, weights in regs
                auto sdsegW = [&](int kbs, short8* W) {
                    short8 a0 = ldA(skx, 132, ln, kbs, lq);
                    short8 a1 = ldA(skx, 132, ln, kbs + 1, lq);
                    SD00 = mf(a0, W[0], SD00); SD10 = mf(a0, W[1], SD10);
                    SD01 = mf(a1, W[2], SD01); SD11 = mf(a1, W[3], SD11);
                };
                auto ldW = [&](int kb, short8* W) {
                    W[0] = ldA(wsd, 164, n0, kb, lq);
                    W[1] = ldA(wsd, 164, n1, kb, lq);
                    W[2] = ldA(wsd, 164, n0, kb + 1, lq);
                    W[3] = ldA(wsd, 164, n1, kb + 1, lq);
                };

                // ====== A: gather + ps/s loads + FW partials (kb0-5) + SD-ps ======
                {
                    __builtin_amdgcn_s_setprio(1);
                    int per = period_s[prow];
#pragma unroll
                    for (int ii = 0; ii < 5; ++ii) {
                        int i = px16 * 5 + ii;
                        if (i < 68) {
                            int idx = LPREV - per + i - 2;
                            if (idx >= LPREV) idx -= per;
                            catb[prow * 424 + 192 + i] = hist[prow * HSTR + ((base + idx) & 511)];
                        }
                    }
                    aps0 = ldA(psb, 36, ln, 0, lq);
                    aps1 = ldA(psb, 36, ln, 1, lq);
                    asg0 = ldA(sgb, 36, ln, 0, lq);
                    asg1 = ldA(sgb, 36, ln, 1, lq);
                    short8 c0 = ldA(catb, 212, ln, 0, lq);
                    short8 c1 = ldA(catb, 212, ln, 1, lq);
                    short8 c2 = ldA(catb, 212, ln, 2, lq);
                    short8 c3 = ldA(catb, 212, ln, 3, lq);
                    floatx4 C0 = mf(c0, BfwP[0], z4);
                    floatx4 C1 = mf(c1, BfwP[1], z4);
                    floatx4 C2 = mf(c2, BfwP[2], z4);
                    floatx4 C3 = mf(c3, BfwP[3], z4);
                    C0 = mf(aps0, BfwP[4], C0);
                    C1 = mf(aps1, BfwP[5], C1);
                    // SD ps segment (kb8,9), weights resident
                    SD00 = mf(aps0, BsdPS[0], SD00);
                    SD10 = mf(aps0, BsdPS[1], SD10);
                    SD01 = mf(aps1, BsdPS[2], SD01);
                    SD11 = mf(aps1, BsdPS[3], SD11);
                    floatx4 s = (C0 + C1) + (C2 + C3);
                    *(floatx4*)&pcFW[w4][lane][0] = s;
                    __builtin_amdgcn_s_setprio(0);
                }
                barx();                                    // A
                // ====== B: GRU1 partials (pure reg) ======
                grupart(0, asg0, asg1);
                barx();                                    // B
                // ====== C: prefetch wsd fw-segment weights ======
                ldW(6, W6);
                barx();                                    // C
                // ====== D: SD fw (kb6,7); prefetch o1 weights ======
                sdsegW(6, W6);
                ldW(0, W0);
                barx();                                    // D
                // ====== E: GRU2 partials ======
                {
                    short8 s0f = ldA(sgb, 36, ln, 0, lq);
                    short8 s1f = ldA(sgb, 36, ln, 1, lq);
                    grupart(1, s0f, s1f);
                }
                barx();                                    // E
                // ====== F: SD o1 (kb0,1); prefetch o2 weights ======
                sdsegW(0, W0);
                ldW(2, W2);
                barx();                                    // F
                // ====== G: GRU3 partials ======
                {
                    short8 s0f = ldA(sgb, 36, ln, 0, lq);
                    short8 s1f = ldA(sgb, 36, ln, 1, lq);
                    grupart(2, s0f, s1f);
                }
                barx();                                    // G
                // ====== H: SD o2 (kb2,3); prefetch o3 weights ======
                sdsegW(2, W2);
                ldW(4, W4);
                barx();                                    // H
                // ====== I: idle ======
                barx();                                    // I
                // ====== J: SD o3 (kb4,5) + tanh -> sdbb ======
                {
                    __builtin_amdgcn_s_setprio(1);
                    sdsegW(4, W4);
                    float t0[4], t1[4];
#pragma unroll
                    for (int r = 0; r < 4; ++r) {
                        t0[r] = ftanh(SD00[r] + SD01[r]);
                        t1[r] = ftanh(SD10[r] + SD11[r]);
                    }
                    st4c(&sdbb[(4 * lq) * 136 + n0], 136, t0[0], t0[1], t0[2], t0[3]);
                    st4c(&sdbb[(4 * lq) * 136 + n1], 136, t1[0], t1[1], t1[2], t1[3]);
                    __builtin_amdgcn_s_setprio(0);
                }
                barx();                                    // J
                // ====== K: SG tile1 ======
                {
                    short8 a0 = ldA(sdbb, 68, ln, 0, lq);
                    short8 a1 = ldA(sdbb, 68, ln, 1, lq);
                    short8 a2 = ldA(sdbb, 68, ln, 2, lq);
                    short8 a3 = ldA(sdbb, 68, ln, 3, lq);
                    floatx4 Cc = mf(a0, Bsg1[0], z4), Cd = mf(a1, Bsg1[1], z4);
                    Cc = mf(a2, Bsg1[2], Cc); Cd = mf(a3, Bsg1[3], Cd);
                    float u1[4];
#pragma unroll
                    for (int r = 0; r < 4; ++r)
                        u1[r] = bf2f(sdbb[(4 * lq + r) * 136 + n1]) * fsig(Cc[r] + Cd[r]);
                    st4c(&sobb[(4 * lq) * 136 + n1], 136, u1[0], u1[1], u1[2], u1[3]);
                }
                barx();                                    // K
                // ====== L: feat2s shuffle + prefetch + period ======
                {
                    unsigned int* cat32 = (unsigned int*)catb;
                    int cb = prow * 212;
                    int u0 = pe8 >> 1;
                    unsigned int o0 = cat32[cb + u0 + 0];
                    unsigned int o1 = cat32[cb + u0 + 1];
                    unsigned int o2 = cat32[cb + u0 + 2];
                    unsigned int o3 = cat32[cb + u0 + 3];
                    cat32[cb + 130 + u0 + 0] = o0;
                    cat32[cb + 130 + u0 + 1] = o1;
                    cat32[cb + 130 + u0 + 2] = o2;
                    cat32[cb + 130 + u0 + 3] = o3;
                    *(uint4*)(cat32 + cb + u0) = pfc;
                    int sN = f * 4 + kk + 2;
                    if (sN > NFRAMES * 4 - 1) sN = NFRAMES * 4 - 1;
                    pfc = *(const uint4*)(cb16
                        + ((size_t)(b0 + prow) * NFRAMES + (sN >> 2)) * 512 + (sN & 3) * 128 + pe8);
                    if (kk == 0 && t < 256 + RPW) {
                        int fN = (f + 1 < NFRAMES) ? f + 1 : f;
                        pper = ld1f(f32, feats,
                                    (size_t)(b0 + (t - 256)) * (NF * NFRAMES) + (NF - 1) * NFRAMES + fN);
                    }
                    if (kk == 3 && t < 256 + RPW) period_s[t - 256] = (int)rintf(pper);
                }
                barx();                                    // L
                base += SS;
            }
        }
    }
}

// ---------- launch ----------
extern "C" void kernel_launch(void* const* d_in, const int* in_sizes, int n_in,
                              void* d_out, int out_size, void* d_ws, size_t ws_size,
                              hipStream_t stream) {
    const void* feats = d_in[0];
    const void* gfeat = d_in[1];
    const void* prev  = d_in[2];
    const void* Wc1   = d_in[3];
    const void* Wc2   = d_in[4];
    const void* Wc3   = d_in[5];
    const void* Wfw   = d_in[6];
    const void* Wfwg  = d_in[7];
    const void* Wih1  = d_in[8];
    const void* Whh1  = d_in[9];
    const void* Wih2  = d_in[10];
    const void* Whh2  = d_in[11];
    const void* Wih3  = d_in[12];
    const void* Whh3  = d_in[13];
    const void* Wg1   = d_in[14];
    const void* Wg2   = d_in[15];
    const void* Wg3   = d_in[16];
    const void* Wsg   = d_in[17];
    const void* Wsd   = d_in[18];
    const void* Wout  = d_in[19];

    int*            flag = (int*)d_ws;                                      // @0
    unsigned short* cb16 = (unsigned short*)((char*)d_ws + 256);            // 6,553,600 B
    unsigned int*   wct  = (unsigned int*)((char*)d_ws + 256 + 6553600);    // 524,288 B
    uint4*          wbuf = (uint4*)((char*)d_ws + 256 + 6553600 + 524288);  // 438,272 B

    fargan_detect<<<1, 1, 0, stream>>>(feats, flag);
    fargan_prep<<<(NFRAG + 255) / 256, 256, 0, stream>>>(flag, Wfw, Wfwg,
        Wih1, Whh1, Wih2, Whh2, Wih3, Whh3, Wg1, Wg2, Wg3, Wsg, Wsd, Wout, wbuf);
    fargan_prep_conv<<<512, 256, 0, stream>>>(flag, Wc1, Wc2, Wc3, wct);
    fargan_conv<<<BATCH * 25, 256, 0, stream>>>(feats, gfeat, flag, wct, cb16);
    fargan_seq<<<BATCH / RPW, 512, 0, stream>>>(feats, prev, flag, cb16, wbuf, d_out);
}